// Round 5
// baseline (565.542 us; speedup 1.0000x reference)
//
#include <hip/hip_runtime.h>
#include <math.h>

#define BSZ   32768
#define FDIM  256
#define HDIM  128
#define OUTD  64
#define SQRT_HALF 0.70710678118654752f
#define BN_EPS 1e-5f
#define SM_EPS 1e-5f
#define INV_B (1.0f / 32768.0f)
#define NCPY  8
#define SLOT  (NCPY * 512)
#define GRID  1024

// swizzled byte offset inside the 32x256 bf16 tile (row-major, 512 B rows)
#define SWZ(r, cb) ((((r) << 9) + (cb)) ^ (((r) & 7) << 4))

typedef __attribute__((ext_vector_type(8))) short bf16x8;
typedef __attribute__((ext_vector_type(4))) short bf16x4;
typedef __attribute__((ext_vector_type(4))) float f32x4;

__device__ __forceinline__ float b2f(unsigned short u) {
    return __uint_as_float(((unsigned int)u) << 16);
}
__device__ __forceinline__ unsigned short f2b(float f) {
    unsigned int u = __float_as_uint(f);
    u += 0x7fff + ((u >> 16) & 1);   // RNE
    return (unsigned short)(u >> 16);
}

__device__ __forceinline__ void async16(const void* g, void* l) {
    __builtin_amdgcn_global_load_lds(
        (const __attribute__((address_space(1))) void*)(uintptr_t)g,
        (__attribute__((address_space(3))) void*)(unsigned int)(uintptr_t)l,
        16, 0, 0);
}

__device__ inline float waveMaxAll(float v) {
#pragma unroll
    for (int m = 32; m > 0; m >>= 1) v = fmaxf(v, __shfl_xor(v, m, 64));
    return v;
}
__device__ inline float waveSumAll(float v) {
#pragma unroll
    for (int m = 32; m > 0; m >>= 1) v += __shfl_xor(v, m, 64);
    return v;
}

// ---- software grid barrier (sense-reversing; requires all blocks co-resident) ----
__device__ __forceinline__ void grid_sync_sw(unsigned int* bar, unsigned int nb) {
    __syncthreads();
    if (threadIdx.x == 0) {
        __threadfence();   // release: prior writes visible at agent scope
        unsigned int gen = __hip_atomic_load(bar + 1, __ATOMIC_RELAXED, __HIP_MEMORY_SCOPE_AGENT);
        unsigned int arr = __hip_atomic_fetch_add(bar, 1u, __ATOMIC_ACQ_REL, __HIP_MEMORY_SCOPE_AGENT);
        if (arr == nb - 1) {
            __hip_atomic_store(bar, 0u, __ATOMIC_RELAXED, __HIP_MEMORY_SCOPE_AGENT);
            __hip_atomic_fetch_add(bar + 1, 1u, __ATOMIC_RELEASE, __HIP_MEMORY_SCOPE_AGENT);
        } else {
            long spin = 0;
            while (__hip_atomic_load(bar + 1, __ATOMIC_ACQUIRE, __HIP_MEMORY_SCOPE_AGENT) == gen) {
                if (++spin > (1L << 24)) break;   // safety net: fail loud, not hung
                __builtin_amdgcn_s_sleep(2);
            }
        }
        __threadfence();
    }
    __syncthreads();
}

// ---- B-tile staging: one 256x32 k-chunk of Wt into Bs ----
__device__ __forceinline__ void stage_B(short* Bs, const unsigned short* __restrict__ Wt,
                                        int K, int k0, int wave, int lane) {
    const int sr = lane >> 2;
    const int sc = (lane & 3) * 8;
#pragma unroll
    for (int t = 0; t < 4; ++t) {
        const int wr = wave * 64 + t * 16 + sr;
        async16(Wt + (size_t)wr * K + k0 + sc, (void*)(Bs + (wave * 4 + t) * 512 + lane * 8));
    }
}

// ---- GEMM core: A (32x256 bf16, swizzled) from buf, B staged per k-step ----
// CONTRACT: caller already issued stage_B(..., k0=0). Ends with a barrier.
__device__ __forceinline__ void gemm_core(const short* buf, short* Bs,
                                          const unsigned short* __restrict__ Wt, int K,
                                          int wave, int lane, f32x4 (&acc)[2][4]) {
    const int fm = lane & 15;
    const int fq = (lane >> 4) * 8;
#pragma unroll
    for (int i = 0; i < 2; ++i)
#pragma unroll
        for (int j = 0; j < 4; ++j)
            acc[i][j] = (f32x4){0.f, 0.f, 0.f, 0.f};

    for (int k0 = 0; k0 < K; k0 += 32) {
        __syncthreads();   // chunk k0 landed in Bs; buf writes visible
        bf16x8 af[2], bfr[4];
#pragma unroll
        for (int i = 0; i < 2; ++i)
            af[i] = *(const bf16x8*)((const char*)buf + SWZ(i * 16 + fm, (k0 + fq) * 2));
#pragma unroll
        for (int j = 0; j < 4; ++j)
            bfr[j] = *(const bf16x8*)(Bs + (wave * 64 + j * 16 + fm) * 32 + fq);
#pragma unroll
        for (int i = 0; i < 2; ++i)
#pragma unroll
            for (int j = 0; j < 4; ++j)
                acc[i][j] = __builtin_amdgcn_mfma_f32_16x16x32_bf16(af[i], bfr[j], acc[i][j], 0, 0, 0);
        __syncthreads();   // all waves done reading Bs/buf for this chunk
        if (k0 + 32 < K) stage_B(Bs, Wt, K, k0 + 32, wave, lane);
    }
}

// ---- epilogue: acc -> buf (bf16, swizzled) + column stats atomics ----
__device__ __forceinline__ void stage_epilogue(f32x4 (&acc)[2][4], short* buf,
                                               float* redS, float* redQ,
                                               float* __restrict__ statsOut,
                                               int wave, int lane, int tid, int bcp) {
    const int fm = lane & 15;
    const int row4 = (lane >> 4) * 4;
    const int ocol = wave * 64 + fm;
#pragma unroll
    for (int i = 0; i < 2; ++i)
#pragma unroll
        for (int j = 0; j < 4; ++j)
#pragma unroll
            for (int r = 0; r < 4; ++r)
                *(short*)((char*)buf + SWZ(row4 + i * 16 + r, (ocol + j * 16) * 2)) =
                    (short)f2b(acc[i][j][r]);

#pragma unroll
    for (int j = 0; j < 4; ++j) {
        float s = 0.f, q = 0.f;
#pragma unroll
        for (int i = 0; i < 2; ++i)
#pragma unroll
            for (int r = 0; r < 4; ++r) {
                float v = acc[i][j][r];
                s += v; q += v * v;
            }
        s += __shfl_xor(s, 16, 64); s += __shfl_xor(s, 32, 64);
        q += __shfl_xor(q, 16, 64); q += __shfl_xor(q, 32, 64);
        if (lane < 16) {
            redS[wave * 64 + j * 16 + lane] = s;
            redQ[wave * 64 + j * 16 + lane] = q;
        }
    }
    __syncthreads();
    atomicAdd(&statsOut[bcp + tid], redS[tid]);
    atomicAdd(&statsOut[bcp + 256 + tid], redQ[tid]);
}

// ---- BN affine tables ----
__device__ __forceinline__ void build_tbl_glu(const float* __restrict__ st,
                                              const float* __restrict__ pg,
                                              const float* __restrict__ pb,
                                              int colOff, int K, int tid, float* tbl) {
    if (tid < K) {
        const int ch = colOff + tid;
        const int cg = ch + 128;
        float sA = 0.f, qA = 0.f, sG = 0.f, qG = 0.f;
#pragma unroll
        for (int cp = 0; cp < NCPY; ++cp) {
            const float* p = st + cp * 512;
            sA += p[ch]; qA += p[256 + ch];
            sG += p[cg]; qG += p[256 + cg];
        }
        float ma = sA * INV_B, va = qA * INV_B - ma * ma;
        float scA = pg[ch] * rsqrtf(va + BN_EPS);
        tbl[tid] = scA; tbl[K + tid] = pb[ch] - ma * scA;
        float mg = sG * INV_B, vg = qG * INV_B - mg * mg;
        float scG = pg[cg] * rsqrtf(vg + BN_EPS);
        tbl[2 * K + tid] = scG; tbl[3 * K + tid] = pb[cg] - mg * scG;
    }
    __syncthreads();
}

__device__ __forceinline__ void build_tbl_mask(const float* __restrict__ st,
                                               const float* __restrict__ gcp,
                                               const float* __restrict__ bcp_,
                                               int tid, float* tbl) {
    float s = 0.f, q = 0.f;
#pragma unroll
    for (int cp = 0; cp < NCPY; ++cp) {
        s += st[cp * 512 + tid];
        q += st[cp * 512 + 256 + tid];
    }
    float mean = s * INV_B, var = q * INV_B - mean * mean;
    float scl = gcp[tid] * rsqrtf(var + BN_EPS);
    tbl[tid] = scl;
    tbl[256 + tid] = bcp_[tid] - mean * scl;
    __syncthreads();
}

// ---- GLU prologue: P-pairs in buf -> BN+GLU(+res) -> A into buf (in place) ----
template <int K, bool RES, bool WH, int RB>
__device__ __forceinline__ void glu_prologue(short* buf, const float* tbl,
                                             int tid, int colOff, bf16x4* h) {
    const int ar = tid >> 3;
    const int ac = (tid & 7) * 4;
#pragma unroll
    for (int c = 0; c < K / 32; ++c) {
        const int kk = c * 32 + ac;
        bf16x4 lo = *(const bf16x4*)((const char*)buf + SWZ(ar, (colOff + kk) * 2));
        bf16x4 hi = *(const bf16x4*)((const char*)buf + SWZ(ar, (colOff + kk + 128) * 2));
        float4 a0 = *(const float4*)&tbl[kk];
        float4 h0 = *(const float4*)&tbl[K + kk];
        float4 g0 = *(const float4*)&tbl[2 * K + kk];
        float4 s0 = *(const float4*)&tbl[3 * K + kk];
        const float scA[4] = {a0.x, a0.y, a0.z, a0.w};
        const float shA[4] = {h0.x, h0.y, h0.z, h0.w};
        const float scG[4] = {g0.x, g0.y, g0.z, g0.w};
        const float shG[4] = {s0.x, s0.y, s0.z, s0.w};
        bf16x4 o4;
#pragma unroll
        for (int e = 0; e < 4; ++e) {
            float na = b2f((unsigned short)lo[e]) * scA[e] + shA[e];
            float ng = b2f((unsigned short)hi[e]) * scG[e] + shG[e];
            float v = na * (1.0f / (1.0f + __expf(-ng)));
            if (RES) v = (v + b2f((unsigned short)h[RB + c][e])) * SQRT_HALF;
            o4[e] = (short)f2b(v);
        }
        *(bf16x4*)((char*)buf + SWZ(ar, kk * 2)) = o4;
        if (WH) h[c] = o4;
    }
}

// ---- mask phase (mega): coef P in buf -> BN -> softmax -> cmpl'/masked/entropy ----
template <int MODE>   // 0 first, 1 middle, 2 entropy-only
__device__ __forceinline__ void mask_phase(short* buf, const float* tbl,
                                           const unsigned short* __restrict__ xb,
                                           unsigned short* cmpl, float* ent, float* went,
                                           int tid, int wave, int lane, int row0, int bid) {
    const int r = tid >> 3;
    const int cq = tid & 7;
    const size_t grow = (size_t)(row0 + r) * 256;

    float l[32];
    float mx = -1e30f;
#pragma unroll
    for (int e = 0; e < 4; ++e) {
        const int c = cq * 32 + e * 8;
        bf16x8 pv = *(const bf16x8*)((const char*)buf + SWZ(r, c * 2));
        bf16x8 cv;
        if (MODE != 0) cv = *(const bf16x8*)(cmpl + grow + c);
        float4 s0 = *(const float4*)&tbl[c], s1 = *(const float4*)&tbl[c + 4];
        float4 h0 = *(const float4*)&tbl[256 + c], h1 = *(const float4*)&tbl[256 + c + 4];
        const float* sp0 = (const float*)&s0; const float* sp1 = (const float*)&s1;
        const float* hp0 = (const float*)&h0; const float* hp1 = (const float*)&h1;
#pragma unroll
        for (int t = 0; t < 8; ++t) {
            float scl = (t < 4) ? sp0[t] : sp1[t - 4];
            float shf = (t < 4) ? hp0[t] : hp1[t - 4];
            float cl = (MODE != 0) ? b2f((unsigned short)cv[t]) : 1.0f;
            float v = (b2f((unsigned short)pv[t]) * scl + shf) * cl;
            l[e * 8 + t] = v;
            mx = fmaxf(mx, v);
        }
    }
    mx = fmaxf(mx, __shfl_xor(mx, 1, 64));
    mx = fmaxf(mx, __shfl_xor(mx, 2, 64));
    mx = fmaxf(mx, __shfl_xor(mx, 4, 64));

    float ssum = 0.f;
#pragma unroll
    for (int i = 0; i < 32; ++i) { l[i] = __expf(l[i] - mx); ssum += l[i]; }
    ssum += __shfl_xor(ssum, 1, 64);
    ssum += __shfl_xor(ssum, 2, 64);
    ssum += __shfl_xor(ssum, 4, 64);
    const float inv = 1.0f / ssum;

    float et = 0.f;
#pragma unroll
    for (int e = 0; e < 4; ++e) {
        const int c = cq * 32 + e * 8;
        bf16x8 xv, cv2;
        if (MODE != 2) xv = *(const bf16x8*)(xb + grow + c);
        if (MODE == 1) cv2 = *(const bf16x8*)(cmpl + grow + c);
        bf16x8 mo, co;
#pragma unroll
        for (int t = 0; t < 8; ++t) {
            float m = l[e * 8 + t] * inv;
            et -= m * __logf(m + SM_EPS);
            if (MODE != 2) {
                float cl = (MODE == 1) ? b2f((unsigned short)cv2[t]) : 1.0f;
                co[t] = (short)f2b(cl * (1.5f - m));
                mo[t] = (short)f2b(m * b2f((unsigned short)xv[t]));
            }
        }
        if (MODE != 2) {
            *(bf16x8*)(cmpl + grow + c) = co;
            *(bf16x8*)((char*)buf + SWZ(r, c * 2)) = mo;
        }
    }
    et += __shfl_xor(et, 1, 64);
    et += __shfl_xor(et, 2, 64);
    et += __shfl_xor(et, 4, 64);
    float wet = waveSumAll(et) * 0.125f;
    if (lane == 0) went[wave] = wet;
    __syncthreads();
    if (tid == 0) {
        float v = went[0] + went[1] + went[2] + went[3];
        atomicAdd(&ent[(bid & 255) << 5], v * (INV_B * 0.2f));
    }
}

// =========================== MEGA (persistent, software grid barrier) ===========================
__global__ __launch_bounds__(256, 4) void mega(
    const float* __restrict__ x,
    const float* __restrict__ enc_g, const float* __restrict__ enc_b,
    const float* __restrict__ g1, const float* __restrict__ b1,
    const float* __restrict__ g2, const float* __restrict__ b2,
    const float* __restrict__ g3, const float* __restrict__ b3,
    const float* __restrict__ g4, const float* __restrict__ b4,
    const float* __restrict__ gc, const float* __restrict__ bc,
    const float* __restrict__ W1f, const float* __restrict__ W2f,
    const float* __restrict__ W3f, const float* __restrict__ W4f,
    const float* __restrict__ Wcf,
    unsigned short* __restrict__ W1t, unsigned short* __restrict__ W2t,
    unsigned short* __restrict__ W3t, unsigned short* __restrict__ W4t,
    unsigned short* __restrict__ Wct,
    unsigned short* __restrict__ xb, unsigned short* __restrict__ cmpl,
    float* __restrict__ stats, float* __restrict__ ent,
    unsigned int* __restrict__ bar,
    float* __restrict__ out)
{
#define GSYNC() grid_sync_sw(bar, GRID)

    __shared__ short buf[32 * 256];   // 16 KB A/P tile (swizzled)
    __shared__ short Bs[256 * 32];    // 16 KB weight staging
    __shared__ float redS[256], redQ[256];
    __shared__ float tbl[512];
    __shared__ float went[4];

    const int tid  = threadIdx.x;
    const int wave = tid >> 6;
    const int lane = tid & 63;
    const int bid  = blockIdx.x;
    const int row0 = bid * 32;
    const int bcp  = (bid & (NCPY - 1)) * 512;

    // ---------- pre-sync: weight prep (blocks 0..135) + x col-stats (all) ----------
    if (bid < 136) {
        const int m = bid >> 3, kz = bid & 7, n = tid;
        const float* src; unsigned short* dst; int K;
        if (m == 0)      { src = W1f;                        dst = W1t;               K = 256; }
        else if (m == 1) { src = W2f;                        dst = W2t;               K = 128; }
        else if (m < 7)  { int i = m - 2;  src = W3f + (size_t)i * 128 * 256; dst = W3t + (size_t)i * 32768; K = 128; }
        else if (m < 12) { int i = m - 7;  src = W4f + (size_t)i * 128 * 256; dst = W4t + (size_t)i * 32768; K = 128; }
        else             { int i = m - 12; src = Wcf + (size_t)i * 64 * 256;  dst = Wct + (size_t)i * 16384; K = 64; }
        const int k0 = kz * 32;
        if (k0 < K)
            for (int k = k0; k < k0 + 32; ++k)
                dst[(size_t)n * K + k] = f2b(src[(size_t)k * 256 + n]);
    }
    {   // col stats of x for this block's 32 rows (buf reused as f32 scratch)
        float* red = (float*)buf;
        const int sub = wave;
        const int c4  = lane << 2;
        float s[4] = {0.f, 0.f, 0.f, 0.f}, q[4] = {0.f, 0.f, 0.f, 0.f};
#pragma unroll 8
        for (int i = 0; i < 8; ++i) {
            const int row = row0 + i * 4 + sub;
            float4 v = *(const float4*)(x + (size_t)row * 256 + c4);
            s[0] += v.x; q[0] += v.x * v.x;
            s[1] += v.y; q[1] += v.y * v.y;
            s[2] += v.z; q[2] += v.z * v.z;
            s[3] += v.w; q[3] += v.w * v.w;
        }
#pragma unroll
        for (int e = 0; e < 4; ++e) {
            red[sub * 512 + c4 + e] = s[e];
            red[sub * 512 + 256 + c4 + e] = q[e];
        }
        __syncthreads();
        float sS = red[tid] + red[512 + tid] + red[1024 + tid] + red[1536 + tid];
        float sQ = red[256 + tid] + red[768 + tid] + red[1280 + tid] + red[1792 + tid];
        atomicAdd(&stats[bcp + tid], sS);
        atomicAdd(&stats[bcp + 256 + tid], sQ);
    }
    GSYNC();

    // ---------- stage 0b: normalize x -> buf + xb + out ----------
    stage_B(Bs, W1t, 256, 0, wave, lane);
    {
        float s = 0.f, q = 0.f;
#pragma unroll
        for (int cp = 0; cp < NCPY; ++cp) {
            s += stats[cp * 512 + tid];
            q += stats[cp * 512 + 256 + tid];
        }
        float mean = s * INV_B, var = q * INV_B - mean * mean;
        float scl = enc_g[tid] * rsqrtf(var + BN_EPS);
        tbl[tid] = scl;
        tbl[256 + tid] = enc_b[tid] - mean * scl;
    }
    __syncthreads();
    {
        const int r = tid >> 3, cq = tid & 7;
        const size_t grow = (size_t)(row0 + r) * 256;
#pragma unroll
        for (int e = 0; e < 4; ++e) {
            const int c = cq * 32 + e * 8;
            float4 xa = *(const float4*)(x + grow + c);
            float4 xc = *(const float4*)(x + grow + c + 4);
            const float xv[8] = {xa.x, xa.y, xa.z, xa.w, xc.x, xc.y, xc.z, xc.w};
            float4 s0 = *(const float4*)&tbl[c], s1 = *(const float4*)&tbl[c + 4];
            float4 f0 = *(const float4*)&tbl[256 + c], f1 = *(const float4*)&tbl[256 + c + 4];
            const float sc[8] = {s0.x, s0.y, s0.z, s0.w, s1.x, s1.y, s1.z, s1.w};
            const float sh[8] = {f0.x, f0.y, f0.z, f0.w, f1.x, f1.y, f1.z, f1.w};
            float n[8];
            bf16x8 o8;
#pragma unroll
            for (int t = 0; t < 8; ++t) {
                n[t] = xv[t] * sc[t] + sh[t];
                o8[t] = (short)f2b(n[t]);
            }
            *(bf16x8*)((char*)buf + SWZ(r, c * 2)) = o8;
            *(bf16x8*)(xb + grow + c) = o8;
            if (c < OUTD) {
                float4 o1 = make_float4(5.f * fmaxf(n[0], 0.f), 5.f * fmaxf(n[1], 0.f),
                                        5.f * fmaxf(n[2], 0.f), 5.f * fmaxf(n[3], 0.f));
                float4 o2 = make_float4(5.f * fmaxf(n[4], 0.f), 5.f * fmaxf(n[5], 0.f),
                                        5.f * fmaxf(n[6], 0.f), 5.f * fmaxf(n[7], 0.f));
                *(float4*)(out + (size_t)(row0 + r) * OUTD + c) = o1;
                *(float4*)(out + (size_t)(row0 + r) * OUTD + c + 4) = o2;
            }
        }
    }

    // ---------- 5 iterations x 5 stages ----------
    f32x4 acc[2][4];
    bf16x4 h[4];

    for (int ni = 0; ni < 5; ++ni) {
        float* s1 = stats + (size_t)(1 + ni * 5 + 0) * SLOT;
        float* s2 = stats + (size_t)(1 + ni * 5 + 1) * SLOT;
        float* s3 = stats + (size_t)(1 + ni * 5 + 2) * SLOT;
        float* s4 = stats + (size_t)(1 + ni * 5 + 3) * SLOT;
        float* s5 = stats + (size_t)(1 + ni * 5 + 4) * SLOT;

        if (ni > 0) {
            stage_B(Bs, W1t, 256, 0, wave, lane);   // chunk-0 DMA under mask compute
            float* s5p = stats + (size_t)(1 + (ni - 1) * 5 + 4) * SLOT;
            build_tbl_mask(s5p, gc + (ni - 1) * 256, bc + (ni - 1) * 256, tid, tbl);
            if (ni == 1)
                mask_phase<0>(buf, tbl, xb, cmpl, ent, went, tid, wave, lane, row0, bid);
            else
                mask_phase<1>(buf, tbl, xb, cmpl, ent, went, tid, wave, lane, row0, bid);
        }
        gemm_core(buf, Bs, W1t, 256, wave, lane, acc);
        stage_epilogue(acc, buf, redS, redQ, s1, wave, lane, tid, bcp);
        GSYNC();

        stage_B(Bs, W2t, 128, 0, wave, lane);
        build_tbl_glu(s1, g1, b1, 0, 128, tid, tbl);
        glu_prologue<128, false, true, 0>(buf, tbl, tid, 0, h);
        gemm_core(buf, Bs, W2t, 128, wave, lane, acc);
        stage_epilogue(acc, buf, redS, redQ, s2, wave, lane, tid, bcp);
        GSYNC();

        {
            const unsigned short* Wt = W3t + (size_t)ni * 32768;
            stage_B(Bs, Wt, 128, 0, wave, lane);
            build_tbl_glu(s2, g2, b2, 0, 128, tid, tbl);
            glu_prologue<128, true, true, 0>(buf, tbl, tid, 0, h);
            gemm_core(buf, Bs, Wt, 128, wave, lane, acc);
            stage_epilogue(acc, buf, redS, redQ, s3, wave, lane, tid, bcp);
        }
        GSYNC();

        {
            const unsigned short* Wt = W4t + (size_t)ni * 32768;
            stage_B(Bs, Wt, 128, 0, wave, lane);
            build_tbl_glu(s3, g3 + ni * 256, b3 + ni * 256, 0, 128, tid, tbl);
            glu_prologue<128, true, true, 0>(buf, tbl, tid, 0, h);
            gemm_core(buf, Bs, Wt, 128, wave, lane, acc);
            stage_epilogue(acc, buf, redS, redQ, s4, wave, lane, tid, bcp);
        }
        GSYNC();

        {
            const unsigned short* Wt = Wct + (size_t)ni * 16384;
            stage_B(Bs, Wt, 64, 0, wave, lane);
            build_tbl_glu(s4, g4 + ni * 256, b4 + ni * 256, 64, 64, tid, tbl);
            glu_prologue<64, true, false, 2>(buf, tbl, tid, 64, h);
            gemm_core(buf, Bs, Wt, 64, wave, lane, acc);
            stage_epilogue(acc, buf, redS, redQ, s5, wave, lane, tid, bcp);
        }
        GSYNC();
    }

    // ---------- final: entropy of the last coef ----------
    build_tbl_mask(stats + (size_t)(1 + 4 * 5 + 4) * SLOT,
                   gc + 4 * 256, bc + 4 * 256, tid, tbl);
    mask_phase<2>(buf, tbl, xb, cmpl, ent, went, tid, wave, lane, row0, bid);
    GSYNC();

    if (bid == 0 && wave == 0) {
        float v = 0.f;
#pragma unroll
        for (int i = 0; i < 4; ++i) v += ent[(lane + 64 * i) << 5];
        v = waveSumAll(v);
        if (lane == 0) out[(size_t)BSZ * OUTD] = v;
    }
#undef GSYNC
}

// ======================= FALLBACK PATH (proven R2 pipeline) =======================
__global__ __launch_bounds__(256) void prep_w(
    const float* __restrict__ W1, const float* __restrict__ W2,
    const float* __restrict__ W3, const float* __restrict__ W4,
    const float* __restrict__ Wc,
    unsigned short* __restrict__ W1t, unsigned short* __restrict__ W2t,
    unsigned short* __restrict__ W3t, unsigned short* __restrict__ W4t,
    unsigned short* __restrict__ Wct)
{
    const int m = blockIdx.x, kz = blockIdx.y, n = threadIdx.x;
    const float* src; unsigned short* dst; int K;
    if (m == 0)      { src = W1;                        dst = W1t;               K = 256; }
    else if (m == 1) { src = W2;                        dst = W2t;               K = 128; }
    else if (m < 7)  { int i = m - 2;  src = W3 + (size_t)i * 128 * 256; dst = W3t + (size_t)i * 32768; K = 128; }
    else if (m < 12) { int i = m - 7;  src = W4 + (size_t)i * 128 * 256; dst = W4t + (size_t)i * 32768; K = 128; }
    else             { int i = m - 12; src = Wc + (size_t)i * 64 * 256;  dst = Wct + (size_t)i * 16384; K = 64; }
    const int k0 = kz * 32;
    if (k0 >= K) return;
    for (int k = k0; k < k0 + 32; ++k)
        dst[(size_t)n * K + k] = f2b(src[(size_t)k * 256 + n]);
}

__global__ __launch_bounds__(256) void colstats(const float* __restrict__ X,
                                                float* __restrict__ st0) {
    __shared__ float red[4][512];
    const int sub = threadIdx.x >> 6;
    const int c4  = (threadIdx.x & 63) << 2;
    float s[4] = {0.f, 0.f, 0.f, 0.f}, q[4] = {0.f, 0.f, 0.f, 0.f};
#pragma unroll 8
    for (int i = 0; i < 8; ++i) {
        const int row = blockIdx.x * 32 + i * 4 + sub;
        float4 v = *(const float4*)(X + (size_t)row * 256 + c4);
        s[0] += v.x; q[0] += v.x * v.x;
        s[1] += v.y; q[1] += v.y * v.y;
        s[2] += v.z; q[2] += v.z * v.z;
        s[3] += v.w; q[3] += v.w * v.w;
    }
#pragma unroll
    for (int e = 0; e < 4; ++e) {
        red[sub][c4 + e] = s[e];
        red[sub][256 + c4 + e] = q[e];
    }
    __syncthreads();
    const int t = threadIdx.x;
    const int cp = (blockIdx.x & (NCPY - 1)) * 512;
    float sS = red[0][t] + red[1][t] + red[2][t] + red[3][t];
    float sQ = red[0][256 + t] + red[1][256 + t] + red[2][256 + t] + red[3][256 + t];
    atomicAdd(&st0[cp + t], sS);
    atomicAdd(&st0[cp + 256 + t], sQ);
}

__global__ __launch_bounds__(256) void norm_x(const float* __restrict__ x,
                                              const float* __restrict__ st0,
                                              const float* __restrict__ g,
                                              const float* __restrict__ b,
                                              unsigned short* __restrict__ xb,
                                              float* __restrict__ out) {
    const int i4 = blockIdx.x * 256 + threadIdx.x;
    const int row = i4 >> 6, c4 = (i4 & 63) << 2;
    float4 xv = *(const float4*)(x + (size_t)row * 256 + c4);
    float sS[4] = {0.f, 0.f, 0.f, 0.f}, sQ[4] = {0.f, 0.f, 0.f, 0.f};
#pragma unroll
    for (int cp = 0; cp < NCPY; ++cp) {
        float4 a = *(const float4*)&st0[cp * 512 + c4];
        float4 q = *(const float4*)&st0[cp * 512 + 256 + c4];
        sS[0] += a.x; sS[1] += a.y; sS[2] += a.z; sS[3] += a.w;
        sQ[0] += q.x; sQ[1] += q.y; sQ[2] += q.z; sQ[3] += q.w;
    }
    float4 gv = *(const float4*)&g[c4];
    float4 bv = *(const float4*)&b[c4];
    const float* xp = (const float*)&xv;
    const float* gp = (const float*)&gv; const float* bp = (const float*)&bv;
    float n[4];
    ushort4 ob;
    unsigned short* obp = (unsigned short*)&ob;
#pragma unroll
    for (int e = 0; e < 4; ++e) {
        float mean = sS[e] * INV_B;
        float var  = sQ[e] * INV_B - mean * mean;
        float sc   = gp[e] * rsqrtf(var + BN_EPS);
        float sh   = bp[e] - mean * sc;
        n[e] = xp[e] * sc + sh;
        obp[e] = f2b(n[e]);
    }
    *(ushort4*)(xb + (size_t)row * 256 + c4) = ob;
    if (c4 < OUTD) {
        float4 ov = make_float4(5.0f * fmaxf(n[0], 0.f), 5.0f * fmaxf(n[1], 0.f),
                                5.0f * fmaxf(n[2], 0.f), 5.0f * fmaxf(n[3], 0.f));
        *(float4*)(out + (size_t)row * OUTD + c4) = ov;
    }
}

__device__ __forceinline__ void gemm_epilogue(
    f32x4 (&acc)[2][4], int row0, int wave, int lane, int tid, int bcp,
    float* redS, float* redQ,
    unsigned short* __restrict__ Pout, float* __restrict__ statsOut)
{
    const int fm = lane & 15;
    const int orow = row0 + (lane >> 4) * 4;
    const int ocol = wave * 64 + fm;
#pragma unroll
    for (int i = 0; i < 2; ++i)
#pragma unroll
        for (int j = 0; j < 4; ++j)
#pragma unroll
            for (int r = 0; r < 4; ++r)
                Pout[(size_t)(orow + i * 16 + r) * 256 + (ocol + j * 16)] = f2b(acc[i][j][r]);

#pragma unroll
    for (int j = 0; j < 4; ++j) {
        float s = 0.f, q = 0.f;
#pragma unroll
        for (int i = 0; i < 2; ++i)
#pragma unroll
            for (int r = 0; r < 4; ++r) {
                float v = acc[i][j][r];
                s += v; q += v * v;
            }
        s += __shfl_xor(s, 16, 64); s += __shfl_xor(s, 32, 64);
        q += __shfl_xor(q, 16, 64); q += __shfl_xor(q, 32, 64);
        if (lane < 16) {
            redS[wave * 64 + j * 16 + lane] = s;
            redQ[wave * 64 + j * 16 + lane] = q;
        }
    }
    __syncthreads();
    atomicAdd(&statsOut[bcp + tid], redS[tid]);
    atomicAdd(&statsOut[bcp + 256 + tid], redQ[tid]);
}

__global__ __launch_bounds__(256) void gemm_bf16(
    const unsigned short* __restrict__ A,
    const unsigned short* __restrict__ Wt, int K,
    unsigned short* __restrict__ P,
    float* __restrict__ statsOut)
{
    __shared__ short As[32 * 32];
    __shared__ short Bs[256 * 32];
    __shared__ float redS[256], redQ[256];

    const int tid  = threadIdx.x;
    const int wave = tid >> 6;
    const int lane = tid & 63;
    const int row0 = blockIdx.x * 32;
    const int bcp  = (blockIdx.x & (NCPY - 1)) * 512;

    const int sr = lane >> 2;
    const int sc = (lane & 3) * 8;
    const int fm = lane & 15;
    const int fq = (lane >> 4) * 8;

    f32x4 acc[2][4];
#pragma unroll
    for (int i = 0; i < 2; ++i)
#pragma unroll
        for (int j = 0; j < 4; ++j)
            acc[i][j] = (f32x4){0.f, 0.f, 0.f, 0.f};

    for (int k0 = 0; k0 < K; k0 += 32) {
        if (wave < 2)
            async16(A + (size_t)(row0 + wave * 16 + sr) * K + k0 + sc,
                    (void*)(As + wave * 512 + lane * 8));
#pragma unroll
        for (int t = 0; t < 4; ++t) {
            const int wr = wave * 64 + t * 16 + sr;
            async16(Wt + (size_t)wr * K + k0 + sc,
                    (void*)(Bs + (wave * 4 + t) * 512 + lane * 8));
        }
        __syncthreads();

        bf16x8 af[2], bfr[4];
#pragma unroll
        for (int i = 0; i < 2; ++i)
            af[i] = *(const bf16x8*)(As + (i * 16 + fm) * 32 + fq);
#pragma unroll
        for (int j = 0; j < 4; ++j)
            bfr[j] = *(const bf16x8*)(Bs + (wave * 64 + j * 16 + fm) * 32 + fq);
#pragma unroll
        for (int i = 0; i < 2; ++i)
#pragma unroll
            for (int j = 0; j < 4; ++j)
                acc[i][j] = __builtin_amdgcn_mfma_f32_16x16x32_bf16(af[i], bfr[j], acc[i][j], 0, 0, 0);
        __syncthreads();
    }

    gemm_epilogue(acc, row0, wave, lane, tid, bcp, redS, redQ, P, statsOut);
}

template <int MODE>
__global__ __launch_bounds__(256) void gemm_mask(
    const unsigned short* Pc,
    const float* __restrict__ cstats,
    const float* __restrict__ gc, const float* __restrict__ bc,
    const unsigned short* __restrict__ xb,
    unsigned short* __restrict__ cmpl,
    float* __restrict__ ent,
    const unsigned short* __restrict__ Wt,
    unsigned short* Pout,
    float* __restrict__ statsOut)
{
    __shared__ short Am[32 * 256];
    __shared__ short Bs[256 * 32];
    __shared__ float redS[256], redQ[256];
    __shared__ float tScl[256], tShf[256];
    __shared__ float went[4];

    const int tid  = threadIdx.x;
    const int wave = tid >> 6;
    const int lane = tid & 63;
    const int row0 = blockIdx.x * 32;
    const int bcp  = (blockIdx.x & (NCPY - 1)) * 512;

    const int sr = lane >> 2;
    const int sc = (lane & 3) * 8;

#pragma unroll
    for (int t = 0; t < 4; ++t) {
        const int wr = wave * 64 + t * 16 + sr;
        async16(Wt + (size_t)wr * 256 + sc,
                (void*)(Bs + (wave * 4 + t) * 512 + lane * 8));
    }

    {
        float s = 0.f, q = 0.f;
#pragma unroll
        for (int cp = 0; cp < NCPY; ++cp) {
            s += cstats[cp * 512 + tid];
            q += cstats[cp * 512 + 256 + tid];
        }
        float mean = s * INV_B, var = q * INV_B - mean * mean;
        float scl_ = gc[tid] * rsqrtf(var + BN_EPS);
        tScl[tid] = scl_;
        tShf[tid] = bc[tid] - mean * scl_;
    }
    __syncthreads();

    const int r  = tid >> 3;
    const int cq = tid & 7;
    const size_t grow = (size_t)(row0 + r) * 256;

    float l[32];
    float mx = -1e30f;
#pragma unroll
    for (int e = 0; e < 4; ++e) {
        const int c = cq * 32 + e * 8;
        bf16x8 pv = *(const bf16x8*)(Pc + grow + c);
        bf16x8 cv;
        if (MODE) cv = *(const bf16x8*)(cmpl + grow + c);
        float4 s0 = *(const float4*)&tScl[c], s1 = *(const float4*)&tScl[c + 4];
        float4 h0 = *(const float4*)&tShf[c], h1 = *(const float4*)&tShf[c + 4];
        const float* sp0 = (const float*)&s0; const float* sp1 = (const float*)&s1;
        const float* hp0 = (const float*)&h0; const float* hp1 = (const float*)&h1;
#pragma unroll
        for (int t = 0; t < 8; ++t) {
            float scl_ = (t < 4) ? sp0[t] : sp1[t - 4];
            float shf_ = (t < 4) ? hp0[t] : hp1[t - 4];
            float cl = MODE ? b2f((unsigned short)cv[t]) : 1.0f;
            float v = (b2f((unsigned short)pv[t]) * scl_ + shf_) * cl;
            l[e * 8 + t] = v;
            mx = fmaxf(mx, v);
        }
    }
    mx = fmaxf(mx, __shfl_xor(mx, 1, 64));
    mx = fmaxf(mx, __shfl_xor(mx, 2, 64));
    mx = fmaxf(mx, __shfl_xor(mx, 4, 64));

    float ssum = 0.f;
#pragma unroll
    for (int i = 0; i < 32; ++i) { l[i] = __expf(l[i] - mx); ssum += l[i]; }
    ssum += __shfl_xor(ssum, 1, 64);
    ssum += __shfl_xor(ssum, 2, 64);
    ssum += __shfl_xor(ssum, 4, 64);
    const float inv = 1.0f / ssum;

    float et = 0.f;
#pragma unroll
    for (int e = 0; e < 4; ++e) {
        const int c = cq * 32 + e * 8;
        bf16x8 xv = *(const bf16x8*)(xb + grow + c);
        bf16x8 cv2;
        if (MODE) cv2 = *(const bf16x8*)(cmpl + grow + c);
        bf16x8 mo, co;
#pragma unroll
        for (int t = 0; t < 8; ++t) {
            float m = l[e * 8 + t] * inv;
            et -= m * __logf(m + SM_EPS);
            float cl = MODE ? b2f((unsigned short)cv2[t]) : 1.0f;
            co[t] = (short)f2b(cl * (1.5f - m));
            mo[t] = (short)f2b(m * b2f((unsigned short)xv[t]));
        }
        *(bf16x8*)(cmpl + grow + c) = co;
        unsigned int byte = (unsigned int)(r * 512 + c * 2);
        byte ^= ((unsigned int)(r & 7)) << 4;
        *(bf16x8*)((char*)Am + byte) = mo;
    }
    et += __shfl_xor(et, 1, 64);
    et += __shfl_xor(et, 2, 64);
    et += __shfl_xor(et, 4, 64);
    float wet = waveSumAll(et) * 0.125f;
    if (lane == 0) went[wave] = wet;
    __syncthreads();
    if (tid == 0) {
        float v = went[0] + went[1] + went[2] + went[3];
        atomicAdd(&ent[(blockIdx.x & 255) << 5], v * (INV_B * 0.2f));
    }

    const int fm = lane & 15;
    const int fq = (lane >> 4) * 8;

    f32x4 acc[2][4];
#pragma unroll
    for (int i = 0; i < 2; ++i)
#pragma unroll
        for (int j = 0; j < 4; ++j)
            acc[i][j] = (f32x4){0.f, 0.f, 0.f, 0.f};

    for (int k0 = 0; k0 < 256; k0 += 32) {
        bf16x8 af[2], bfr[4];
#pragma unroll
        for (int i = 0; i < 2; ++i) {
            const int row = i * 16 + fm;
            unsigned int byte = (unsigned int)(row * 512 + (k0 + fq) * 2);
            byte ^= ((unsigned int)(row & 7)) << 4;
            af[i] = *(const bf16x8*)((const char*)Am + byte);
        }
#pragma unroll
        for (int j = 0; j < 4; ++j)
            bfr[j] = *(const bf16x8*)(Bs + (wave * 64 + j * 16 + fm) * 32 + fq);
#pragma unroll
        for (int i = 0; i < 2; ++i)
#pragma unroll
            for (int j = 0; j < 4; ++j)
                acc[i][j] = __builtin_amdgcn_mfma_f32_16x16x32_bf16(af[i], bfr[j], acc[i][j], 0, 0, 0);
        __syncthreads();
        if (k0 + 32 < 256) {
#pragma unroll
            for (int t = 0; t < 4; ++t) {
                const int wr = wave * 64 + t * 16 + sr;
                async16(Wt + (size_t)wr * 256 + (k0 + 32) + sc,
                        (void*)(Bs + (wave * 4 + t) * 512 + lane * 8));
            }
            __syncthreads();
        }
    }

    gemm_epilogue(acc, row0, wave, lane, tid, bcp, redS, redQ, Pout, statsOut);
}

template <bool RES, bool WRITE_H>
__global__ __launch_bounds__(256) void gemm_glu(
    const unsigned short* __restrict__ Pprev,
    const float* __restrict__ pstats,
    const float* __restrict__ pg,
    const float* __restrict__ pb,
    const unsigned short* __restrict__ res,
    int colOff,
    const unsigned short* __restrict__ Wt, int K,
    unsigned short* __restrict__ Pout,
    float* __restrict__ statsOut,
    unsigned short* __restrict__ hOut)
{
    __shared__ short As[32 * 32];
    __shared__ short Bs[256 * 32];
    __shared__ float redS[256], redQ[256];
    __shared__ float tScA[128], tShA[128], tScG[128], tShG[128];

    const int tid  = threadIdx.x;
    const int wave = tid >> 6;
    const int lane = tid & 63;
    const int row0 = blockIdx.x * 32;
    const int bcp  = (blockIdx.x & (NCPY - 1)) * 512;

    if (tid < K) {
        const int ch = colOff + tid;
        const int cg = ch + 128;
        float sA = 0.f, qA = 0.f, sG = 0.f, qG = 0.f;
#pragma unroll
        for (int cp = 0; cp < NCPY; ++cp) {
            const float* p = pstats + cp * 512;
            sA += p[ch]; qA += p[256 + ch];
            sG += p[cg]; qG += p[256 + cg];
        }
        float ma = sA * INV_B, va = qA * INV_B - ma * ma;
        float scA = pg[ch] * rsqrtf(va + BN_EPS);
        tScA[tid] = scA; tShA[tid] = pb[ch] - ma * scA;
        float mg = sG * INV_B, vg = qG * INV_B - mg * mg;
        float scG = pg[cg] * rsqrtf(vg + BN_EPS);
        tScG[tid] = scG; tShG[tid] = pb[cg] - mg * scG;
    }
    __syncthreads();

    const int sr = lane >> 2;
    const int sc = (lane & 3) * 8;
    const int ar = tid >> 3;
    const int ac = (tid & 7) * 4;
    const int fm = lane & 15;
    const int fq = (lane >> 4) * 8;

    f32x4 acc[2][4];
#pragma unroll
    for (int i = 0; i < 2; ++i)
#pragma unroll
        for (int j = 0; j < 4; ++j)
            acc[i][j] = (f32x4){0.f, 0.f, 0.f, 0.f};

    for (int k0 = 0; k0 < K; k0 += 32) {
#pragma unroll
        for (int t = 0; t < 4; ++t) {
            const int wr = wave * 64 + t * 16 + sr;
            async16(Wt + (size_t)wr * K + k0 + sc,
                    (void*)(Bs + (wave * 4 + t) * 512 + lane * 8));
        }

        {
            const int kk = k0 + ac;
            const size_t grow = (size_t)(row0 + ar);

            bf16x4 lo = *(const bf16x4*)(Pprev + grow * 256 + colOff + kk);
            bf16x4 hi = *(const bf16x4*)(Pprev + grow * 256 + colOff + kk + 128);
            bf16x4 rv;
            if (RES) rv = *(const bf16x4*)(res + grow * 128 + kk);

            float4 a0 = *(const float4*)&tScA[kk];
            float4 h0 = *(const float4*)&tShA[kk];
            float4 g0 = *(const float4*)&tScG[kk];
            float4 s0 = *(const float4*)&tShG[kk];
            float scA[4] = {a0.x, a0.y, a0.z, a0.w};
            float shA[4] = {h0.x, h0.y, h0.z, h0.w};
            float scG[4] = {g0.x, g0.y, g0.z, g0.w};
            float shG[4] = {s0.x, s0.y, s0.z, s0.w};

            bf16x4 o4;
#pragma unroll
            for (int e = 0; e < 4; ++e) {
                float na = b2f((unsigned short)lo[e]) * scA[e] + shA[e];
                float ng = b2f((unsigned short)hi[e]) * scG[e] + shG[e];
                float v = na * (1.0f / (1.0f + __expf(-ng)));
                if (RES) v = (v + b2f((unsigned short)rv[e])) * SQRT_HALF;
                o4[e] = (short)f2b(v);
            }
            *(bf16x4*)(As + ar * 32 + ac) = o4;
            if (WRITE_H)
                *(bf16x4*)(hOut + grow * 128 + kk) = o4;
        }
        __syncthreads();

        bf16x8 af[2], bfr[4];
#pragma unroll
        for (int i = 0; i < 2; ++i)
            af[i] = *(const bf16x8*)(As + (i * 16 + fm) * 32 + fq);
#pragma unroll
        for (int j = 0; j < 4; ++j)
            bfr[j] = *(const bf16x8*)(Bs + (wave * 64 + j * 16 + fm) * 32 + fq);
#pragma unroll
        for (int i = 0; i < 2; ++i)
#pragma unroll
            for (int j = 0; j < 4; ++j)
                acc[i][j] = __builtin_amdgcn_mfma_f32_16x16x32_bf16(af[i], bfr[j], acc[i][j], 0, 0, 0);
        __syncthreads();
    }

    gemm_epilogue(acc, row0, wave, lane, tid, bcp, redS, redQ, Pout, statsOut);
}

__global__ __launch_bounds__(256) void coef_ent(const unsigned short* __restrict__ Pc,
                                                const float* __restrict__ stats,
                                                const float* __restrict__ gc,
                                                const float* __restrict__ bc,
                                                const unsigned short* __restrict__ cmpl,
                                                float* __restrict__ ent) {
    const int w    = threadIdx.x >> 6;
    const int lane = threadIdx.x & 63;
    const int row  = blockIdx.x * 4 + w;
    const int c    = lane << 2;
    __shared__ float went[4];

    float sS[4] = {0.f, 0.f, 0.f, 0.f}, sQ[4] = {0.f, 0.f, 0.f, 0.f};
#pragma unroll
    for (int cp = 0; cp < NCPY; ++cp) {
        float4 a = *(const float4*)&stats[cp * 512 + c];
        float4 q = *(const float4*)&stats[cp * 512 + 256 + c];
        sS[0] += a.x; sS[1] += a.y; sS[2] += a.z; sS[3] += a.w;
        sQ[0] += q.x; sQ[1] += q.y; sQ[2] += q.z; sQ[3] += q.w;
    }
    float4 gv = *(const float4*)&gc[c];
    float4 bv = *(const float4*)&bc[c];
    const float* gvv = (const float*)&gv; const float* bvv = (const float*)&bv;

    float scl[4], shf[4];
#pragma unroll
    for (int e = 0; e < 4; ++e) {
        float mean = sS[e] * INV_B, var = sQ[e] * INV_B - mean * mean;
        scl[e] = gvv[e] * rsqrtf(var + BN_EPS);
        shf[e] = bvv[e] - mean * scl[e];
    }

    const size_t idx = (size_t)row * 256 + c;
    ushort4 pu = *(const ushort4*)(Pc + idx);
    const unsigned short* puv = (const unsigned short*)&pu;
    ushort4 cu = *(const ushort4*)(cmpl + idx);
    const unsigned short* cuv = (const unsigned short*)&cu;

    float l[4];
#pragma unroll
    for (int e = 0; e < 4; ++e)
        l[e] = (b2f(puv[e]) * scl[e] + shf[e]) * b2f(cuv[e]);

    float mx = waveMaxAll(fmaxf(fmaxf(l[0], l[1]), fmaxf(l[2], l[3])));
    float e0 = __expf(l[0] - mx), e1 = __expf(l[1] - mx),
          e2 = __expf(l[2] - mx), e3 = __expf(l[3] - mx);
    float inv = 1.0f / waveSumAll(e0 + e1 + e2 + e3);

    float m[4] = {e0 * inv, e1 * inv, e2 * inv, e3 * inv};

    float et = -m[0] * __logf(m[0] + SM_EPS) - m[1] * __logf(m[1] + SM_EPS)
             - m[2] * __logf(m[2] + SM_EPS) - m[3] * __logf(m[3] + SM_EPS);
    et = waveSumAll(et);
    if (lane == 0) went[w] = et;
    __syncthreads();
    if (threadIdx.x == 0) {
        float v = went[0] + went[1] + went[2] + went[3];
        atomicAdd(&ent[(blockIdx.x & 255) << 5], v * (INV_B * 0.2f));
    }
}

__global__ __launch_bounds__(64) void write_ent(const float* __restrict__ ent,
                                                float* __restrict__ dst) {
    const int lane = threadIdx.x;
    float v = 0.f;
#pragma unroll
    for (int i = 0; i < 4; ++i) v += ent[(lane + 64 * i) << 5];
    v = waveSumAll(v);
    if (lane == 0) dst[0] = v;
}

// ---------------- host orchestration ----------------
extern "C" void kernel_launch(void* const* d_in, const int* in_sizes, int n_in,
                              void* d_out, int out_size, void* d_ws, size_t ws_size,
                              hipStream_t stream) {
    const float* x     = (const float*)d_in[0];
    const float* enc_g = (const float*)d_in[1];
    const float* enc_b = (const float*)d_in[2];
    const float* W1 = (const float*)d_in[3];
    const float* g1 = (const float*)d_in[4];
    const float* b1 = (const float*)d_in[5];
    const float* W2 = (const float*)d_in[6];
    const float* g2 = (const float*)d_in[7];
    const float* b2 = (const float*)d_in[8];
    const float* W3 = (const float*)d_in[9];
    const float* g3 = (const float*)d_in[10];
    const float* b3 = (const float*)d_in[11];
    const float* W4 = (const float*)d_in[12];
    const float* g4 = (const float*)d_in[13];
    const float* b4 = (const float*)d_in[14];
    const float* Wc = (const float*)d_in[15];
    const float* gc = (const float*)d_in[16];
    const float* bc = (const float*)d_in[17];
    float* out = (float*)d_out;

    const size_t NBF = (size_t)BSZ * FDIM;
    const size_t NBH = (size_t)BSZ * HDIM;

    unsigned short* xb     = (unsigned short*)d_ws;
    unsigned short* masked = xb + NBF;            // fallback ping buffer; mega: bar lives here
    unsigned short* Pb1    = masked + NBF;
    unsigned short* h1     = Pb1 + NBF;
    unsigned short* h2     = h1 + NBH;
    unsigned short* h3     = h2 + NBH;
    unsigned short* cmpl   = h3 + NBH;
    unsigned short* W1t    = cmpl + NBF;
    unsigned short* W2t    = W1t + 65536;
    unsigned short* W3t    = W2t + 32768;
    unsigned short* W4t    = W3t + 163840;
    unsigned short* Wct    = W4t + 163840;
    float* stats = (float*)(Wct + 81920);
    float* ent   = stats + 26 * SLOT;
    unsigned int* bar = (unsigned int*)masked;    // 8 bytes, mega path only

    unsigned short* Pb2 = masked;

    // one-time occupancy check (host-side query; capture-safe)
    static int s_ok = -1;
    if (s_ok < 0) {
        int occ = 0, mpc = 0, dev = 0;
        hipGetDevice(&dev);
        hipDeviceProp_t prop;
        if (hipGetDeviceProperties(&prop, dev) == hipSuccess) mpc = prop.multiProcessorCount;
        if (hipOccupancyMaxActiveBlocksPerMultiprocessor(
                &occ, reinterpret_cast<const void*>(mega), 256, 0) != hipSuccess) occ = 0;
        s_ok = (occ >= 4 && occ * mpc >= GRID) ? 1 : 0;
    }

    hipMemsetAsync(stats, 0, (26 * SLOT + 256 * 32) * sizeof(float), stream);

    if (s_ok) {
        hipMemsetAsync(bar, 0, 2 * sizeof(unsigned int), stream);
        mega<<<GRID, 256, 0, stream>>>(
            x, enc_g, enc_b, g1, b1, g2, b2, g3, b3, g4, b4, gc, bc,
            W1, W2, W3, W4, Wc, W1t, W2t, W3t, W4t, Wct,
            xb, cmpl, stats, ent, bar, out);
        return;
    }

    // -------- fallback: proven multi-kernel pipeline --------
    prep_w<<<dim3(17, 8), 256, 0, stream>>>(W1, W2, W3, W4, Wc, W1t, W2t, W3t, W4t, Wct);
    colstats<<<1024, 256, 0, stream>>>(x, stats);
    norm_x<<<8192, 256, 0, stream>>>(x, stats, enc_g, enc_b, xb, out);

    for (int ni = 0; ni < 5; ++ni) {
        float* s1 = stats + (size_t)(1 + ni * 5 + 0) * SLOT;
        float* s2 = stats + (size_t)(1 + ni * 5 + 1) * SLOT;
        float* s3 = stats + (size_t)(1 + ni * 5 + 2) * SLOT;
        float* s4 = stats + (size_t)(1 + ni * 5 + 3) * SLOT;
        float* s5 = stats + (size_t)(1 + ni * 5 + 4) * SLOT;

        if (ni == 0) {
            gemm_bf16<<<1024, 256, 0, stream>>>(xb, W1t, 256, Pb1, s1);
        } else {
            float* s5p = stats + (size_t)(1 + (ni - 1) * 5 + 4) * SLOT;
            if (ni == 1)
                gemm_mask<0><<<1024, 256, 0, stream>>>(
                    Pb1, s5p, gc, bc, xb, cmpl, ent, W1t, Pb1, s1);
            else
                gemm_mask<1><<<1024, 256, 0, stream>>>(
                    Pb1, s5p, gc + (ni - 1) * 256, bc + (ni - 1) * 256,
                    xb, cmpl, ent, W1t, Pb1, s1);
        }

        gemm_glu<false, true><<<1024, 256, 0, stream>>>(
            Pb1, s1, g1, b1, nullptr, 0, W2t, 128, Pb2, s2, h1);
        gemm_glu<true, true><<<1024, 256, 0, stream>>>(
            Pb2, s2, g2, b2, h1, 0, W3t + (size_t)ni * 32768, 128, Pb1, s3, h2);
        gemm_glu<true, true><<<1024, 256, 0, stream>>>(
            Pb1, s3, g3 + ni * 256, b3 + ni * 256, h2, 0,
            W4t + (size_t)ni * 32768, 128, Pb2, s4, h3);
        gemm_glu<true, false><<<1024, 256, 0, stream>>>(
            Pb2, s4, g4 + ni * 256, b4 + ni * 256, h3 + 64, 64,
            Wct + (size_t)ni * 16384, 64, Pb1, s5, nullptr);
    }

    coef_ent<<<BSZ / 4, 256, 0, stream>>>(
        Pb1, stats + (size_t)(1 + 4 * 5 + 4) * SLOT,
        gc + 4 * 256, bc + 4 * 256, cmpl, ent);

    write_ent<<<1, 64, 0, stream>>>(ent, out + (size_t)BSZ * OUTD);
}

// Round 6
// 560.215 us; speedup vs baseline: 1.0095x; 1.0095x over previous
//
#include <hip/hip_runtime.h>
#include <math.h>

#define BSZ   32768
#define FDIM  256
#define HDIM  128
#define OUTD  64
#define SQRT_HALF 0.70710678118654752f
#define BN_EPS 1e-5f
#define SM_EPS 1e-5f
#define INV_B (1.0f / 32768.0f)
#define NCPY  8
#define SLOT  (NCPY * 512)
#define GRID  1024

// swizzled byte offset inside the 32x256 bf16 tile (row-major, 512 B rows)
#define SWZ(r, cb) ((((r) << 9) + (cb)) ^ (((r) & 7) << 4))

typedef __attribute__((ext_vector_type(8))) short bf16x8;
typedef __attribute__((ext_vector_type(4))) short bf16x4;
typedef __attribute__((ext_vector_type(4))) float f32x4;

__device__ __forceinline__ float b2f(unsigned short u) {
    return __uint_as_float(((unsigned int)u) << 16);
}
__device__ __forceinline__ unsigned short f2b(float f) {
    unsigned int u = __float_as_uint(f);
    u += 0x7fff + ((u >> 16) & 1);   // RNE
    return (unsigned short)(u >> 16);
}

__device__ __forceinline__ void async16(const void* g, void* l) {
    __builtin_amdgcn_global_load_lds(
        (const __attribute__((address_space(1))) void*)(uintptr_t)g,
        (__attribute__((address_space(3))) void*)(unsigned int)(uintptr_t)l,
        16, 0, 0);
}

__device__ inline float waveMaxAll(float v) {
#pragma unroll
    for (int m = 32; m > 0; m >>= 1) v = fmaxf(v, __shfl_xor(v, m, 64));
    return v;
}
__device__ inline float waveSumAll(float v) {
#pragma unroll
    for (int m = 32; m > 0; m >>= 1) v += __shfl_xor(v, m, 64);
    return v;
}

// ---- spread-tree grid barrier ----
// arr: 64 monotonic counters, one 128B line each (zeroed by host each launch).
// Block bid increments arr[bid & 63]; each of 1024 blocks maps to one of 64
// groups of 16. Wave 0 polls all 64 counters (one lane each) until every
// counter >= want (= gen*16). Monotonic counters => no reset race; a fast
// block's gen+1 increment only makes values larger, which cannot stall a
// gen-N poller.
__device__ __forceinline__ void grid_sync_tree(unsigned int* arr, unsigned int want,
                                               int bid, int tid) {
    __syncthreads();                 // all block ops complete (drains vmcnt too)
    if (tid == 0) {
        __threadfence();             // release: prior global writes visible
        __hip_atomic_fetch_add(&arr[(bid & 63) << 5], 1u,
                               __ATOMIC_RELEASE, __HIP_MEMORY_SCOPE_AGENT);
    }
    if (tid < 64) {
        unsigned int* p = &arr[tid << 5];
        long spin = 0;
        while (__hip_atomic_load(p, __ATOMIC_ACQUIRE, __HIP_MEMORY_SCOPE_AGENT) < want) {
            if (++spin > (1L << 24)) break;   // safety net: fail loud, not hung
            __builtin_amdgcn_s_sleep(1);
        }
        __threadfence();             // acquire side: invalidate stale L1
    }
    __syncthreads();
}

// ---- B-tile staging: one 256x32 k-chunk of Wt into Bs ----
__device__ __forceinline__ void stage_B(short* Bs, const unsigned short* __restrict__ Wt,
                                        int K, int k0, int wave, int lane) {
    const int sr = lane >> 2;
    const int sc = (lane & 3) * 8;
#pragma unroll
    for (int t = 0; t < 4; ++t) {
        const int wr = wave * 64 + t * 16 + sr;
        async16(Wt + (size_t)wr * K + k0 + sc, (void*)(Bs + (wave * 4 + t) * 512 + lane * 8));
    }
}

// ---- GEMM core: A (32x256 bf16, swizzled) from buf, B staged per k-step ----
// CONTRACT: caller already issued stage_B(..., k0=0). Ends with a barrier.
__device__ __forceinline__ void gemm_core(const short* buf, short* Bs,
                                          const unsigned short* __restrict__ Wt, int K,
                                          int wave, int lane, f32x4 (&acc)[2][4]) {
    const int fm = lane & 15;
    const int fq = (lane >> 4) * 8;
#pragma unroll
    for (int i = 0; i < 2; ++i)
#pragma unroll
        for (int j = 0; j < 4; ++j)
            acc[i][j] = (f32x4){0.f, 0.f, 0.f, 0.f};

    for (int k0 = 0; k0 < K; k0 += 32) {
        __syncthreads();   // chunk k0 landed in Bs; buf writes visible
        bf16x8 af[2], bfr[4];
#pragma unroll
        for (int i = 0; i < 2; ++i)
            af[i] = *(const bf16x8*)((const char*)buf + SWZ(i * 16 + fm, (k0 + fq) * 2));
#pragma unroll
        for (int j = 0; j < 4; ++j)
            bfr[j] = *(const bf16x8*)(Bs + (wave * 64 + j * 16 + fm) * 32 + fq);
#pragma unroll
        for (int i = 0; i < 2; ++i)
#pragma unroll
            for (int j = 0; j < 4; ++j)
                acc[i][j] = __builtin_amdgcn_mfma_f32_16x16x32_bf16(af[i], bfr[j], acc[i][j], 0, 0, 0);
        __syncthreads();   // all waves done reading Bs/buf for this chunk
        if (k0 + 32 < K) stage_B(Bs, Wt, K, k0 + 32, wave, lane);
    }
}

// ---- epilogue: acc -> buf (bf16, swizzled) + column stats atomics ----
__device__ __forceinline__ void stage_epilogue(f32x4 (&acc)[2][4], short* buf,
                                               float* redS, float* redQ,
                                               float* __restrict__ statsOut,
                                               int wave, int lane, int tid, int bcp) {
    const int fm = lane & 15;
    const int row4 = (lane >> 4) * 4;
    const int ocol = wave * 64 + fm;
#pragma unroll
    for (int i = 0; i < 2; ++i)
#pragma unroll
        for (int j = 0; j < 4; ++j)
#pragma unroll
            for (int r = 0; r < 4; ++r)
                *(short*)((char*)buf + SWZ(row4 + i * 16 + r, (ocol + j * 16) * 2)) =
                    (short)f2b(acc[i][j][r]);

#pragma unroll
    for (int j = 0; j < 4; ++j) {
        float s = 0.f, q = 0.f;
#pragma unroll
        for (int i = 0; i < 2; ++i)
#pragma unroll
            for (int r = 0; r < 4; ++r) {
                float v = acc[i][j][r];
                s += v; q += v * v;
            }
        s += __shfl_xor(s, 16, 64); s += __shfl_xor(s, 32, 64);
        q += __shfl_xor(q, 16, 64); q += __shfl_xor(q, 32, 64);
        if (lane < 16) {
            redS[wave * 64 + j * 16 + lane] = s;
            redQ[wave * 64 + j * 16 + lane] = q;
        }
    }
    __syncthreads();
    atomicAdd(&statsOut[bcp + tid], redS[tid]);
    atomicAdd(&statsOut[bcp + 256 + tid], redQ[tid]);
}

// ---- BN affine tables ----
__device__ __forceinline__ void build_tbl_glu(const float* __restrict__ st,
                                              const float* __restrict__ pg,
                                              const float* __restrict__ pb,
                                              int colOff, int K, int tid, float* tbl) {
    if (tid < K) {
        const int ch = colOff + tid;
        const int cg = ch + 128;
        float sA = 0.f, qA = 0.f, sG = 0.f, qG = 0.f;
#pragma unroll
        for (int cp = 0; cp < NCPY; ++cp) {
            const float* p = st + cp * 512;
            sA += p[ch]; qA += p[256 + ch];
            sG += p[cg]; qG += p[256 + cg];
        }
        float ma = sA * INV_B, va = qA * INV_B - ma * ma;
        float scA = pg[ch] * rsqrtf(va + BN_EPS);
        tbl[tid] = scA; tbl[K + tid] = pb[ch] - ma * scA;
        float mg = sG * INV_B, vg = qG * INV_B - mg * mg;
        float scG = pg[cg] * rsqrtf(vg + BN_EPS);
        tbl[2 * K + tid] = scG; tbl[3 * K + tid] = pb[cg] - mg * scG;
    }
    __syncthreads();
}

__device__ __forceinline__ void build_tbl_mask(const float* __restrict__ st,
                                               const float* __restrict__ gcp,
                                               const float* __restrict__ bcp_,
                                               int tid, float* tbl) {
    float s = 0.f, q = 0.f;
#pragma unroll
    for (int cp = 0; cp < NCPY; ++cp) {
        s += st[cp * 512 + tid];
        q += st[cp * 512 + 256 + tid];
    }
    float mean = s * INV_B, var = q * INV_B - mean * mean;
    float scl = gcp[tid] * rsqrtf(var + BN_EPS);
    tbl[tid] = scl;
    tbl[256 + tid] = bcp_[tid] - mean * scl;
    __syncthreads();
}

// ---- GLU prologue: P-pairs in buf -> BN+GLU(+res) -> A into buf (in place) ----
template <int K, bool RES, bool WH, int RB>
__device__ __forceinline__ void glu_prologue(short* buf, const float* tbl,
                                             int tid, int colOff, bf16x4* h) {
    const int ar = tid >> 3;
    const int ac = (tid & 7) * 4;
#pragma unroll
    for (int c = 0; c < K / 32; ++c) {
        const int kk = c * 32 + ac;
        bf16x4 lo = *(const bf16x4*)((const char*)buf + SWZ(ar, (colOff + kk) * 2));
        bf16x4 hi = *(const bf16x4*)((const char*)buf + SWZ(ar, (colOff + kk + 128) * 2));
        float4 a0 = *(const float4*)&tbl[kk];
        float4 h0 = *(const float4*)&tbl[K + kk];
        float4 g0 = *(const float4*)&tbl[2 * K + kk];
        float4 s0 = *(const float4*)&tbl[3 * K + kk];
        const float scA[4] = {a0.x, a0.y, a0.z, a0.w};
        const float shA[4] = {h0.x, h0.y, h0.z, h0.w};
        const float scG[4] = {g0.x, g0.y, g0.z, g0.w};
        const float shG[4] = {s0.x, s0.y, s0.z, s0.w};
        bf16x4 o4;
#pragma unroll
        for (int e = 0; e < 4; ++e) {
            float na = b2f((unsigned short)lo[e]) * scA[e] + shA[e];
            float ng = b2f((unsigned short)hi[e]) * scG[e] + shG[e];
            float v = na * (1.0f / (1.0f + __expf(-ng)));
            if (RES) v = (v + b2f((unsigned short)h[RB + c][e])) * SQRT_HALF;
            o4[e] = (short)f2b(v);
        }
        *(bf16x4*)((char*)buf + SWZ(ar, kk * 2)) = o4;
        if (WH) h[c] = o4;
    }
}

// ---- mask phase (mega): coef P in buf -> BN -> softmax -> cmpl'/masked/entropy ----
template <int MODE>   // 0 first, 1 middle, 2 entropy-only
__device__ __forceinline__ void mask_phase(short* buf, const float* tbl,
                                           const unsigned short* __restrict__ xb,
                                           unsigned short* cmpl, float* ent, float* went,
                                           int tid, int wave, int lane, int row0, int bid) {
    const int r = tid >> 3;
    const int cq = tid & 7;
    const size_t grow = (size_t)(row0 + r) * 256;

    float l[32];
    float mx = -1e30f;
#pragma unroll
    for (int e = 0; e < 4; ++e) {
        const int c = cq * 32 + e * 8;
        bf16x8 pv = *(const bf16x8*)((const char*)buf + SWZ(r, c * 2));
        bf16x8 cv;
        if (MODE != 0) cv = *(const bf16x8*)(cmpl + grow + c);
        float4 s0 = *(const float4*)&tbl[c], s1 = *(const float4*)&tbl[c + 4];
        float4 h0 = *(const float4*)&tbl[256 + c], h1 = *(const float4*)&tbl[256 + c + 4];
        const float* sp0 = (const float*)&s0; const float* sp1 = (const float*)&s1;
        const float* hp0 = (const float*)&h0; const float* hp1 = (const float*)&h1;
#pragma unroll
        for (int t = 0; t < 8; ++t) {
            float scl = (t < 4) ? sp0[t] : sp1[t - 4];
            float shf = (t < 4) ? hp0[t] : hp1[t - 4];
            float cl = (MODE != 0) ? b2f((unsigned short)cv[t]) : 1.0f;
            float v = (b2f((unsigned short)pv[t]) * scl + shf) * cl;
            l[e * 8 + t] = v;
            mx = fmaxf(mx, v);
        }
    }
    mx = fmaxf(mx, __shfl_xor(mx, 1, 64));
    mx = fmaxf(mx, __shfl_xor(mx, 2, 64));
    mx = fmaxf(mx, __shfl_xor(mx, 4, 64));

    float ssum = 0.f;
#pragma unroll
    for (int i = 0; i < 32; ++i) { l[i] = __expf(l[i] - mx); ssum += l[i]; }
    ssum += __shfl_xor(ssum, 1, 64);
    ssum += __shfl_xor(ssum, 2, 64);
    ssum += __shfl_xor(ssum, 4, 64);
    const float inv = 1.0f / ssum;

    float et = 0.f;
#pragma unroll
    for (int e = 0; e < 4; ++e) {
        const int c = cq * 32 + e * 8;
        bf16x8 xv, cv2;
        if (MODE != 2) xv = *(const bf16x8*)(xb + grow + c);
        if (MODE == 1) cv2 = *(const bf16x8*)(cmpl + grow + c);
        bf16x8 mo, co;
#pragma unroll
        for (int t = 0; t < 8; ++t) {
            float m = l[e * 8 + t] * inv;
            et -= m * __logf(m + SM_EPS);
            if (MODE != 2) {
                float cl = (MODE == 1) ? b2f((unsigned short)cv2[t]) : 1.0f;
                co[t] = (short)f2b(cl * (1.5f - m));
                mo[t] = (short)f2b(m * b2f((unsigned short)xv[t]));
            }
        }
        if (MODE != 2) {
            *(bf16x8*)(cmpl + grow + c) = co;
            *(bf16x8*)((char*)buf + SWZ(r, c * 2)) = mo;
        }
    }
    et += __shfl_xor(et, 1, 64);
    et += __shfl_xor(et, 2, 64);
    et += __shfl_xor(et, 4, 64);
    float wet = waveSumAll(et) * 0.125f;
    if (lane == 0) went[wave] = wet;
    __syncthreads();
    if (tid == 0) {
        float v = went[0] + went[1] + went[2] + went[3];
        atomicAdd(&ent[(bid & 255) << 5], v * (INV_B * 0.2f));
    }
}

// =========================== MEGA (persistent, spread-tree grid barrier) ===========================
__global__ __launch_bounds__(256, 4) void mega(
    const float* __restrict__ x,
    const float* __restrict__ enc_g, const float* __restrict__ enc_b,
    const float* __restrict__ g1, const float* __restrict__ b1,
    const float* __restrict__ g2, const float* __restrict__ b2,
    const float* __restrict__ g3, const float* __restrict__ b3,
    const float* __restrict__ g4, const float* __restrict__ b4,
    const float* __restrict__ gc, const float* __restrict__ bc,
    const float* __restrict__ W1f, const float* __restrict__ W2f,
    const float* __restrict__ W3f, const float* __restrict__ W4f,
    const float* __restrict__ Wcf,
    unsigned short* __restrict__ W1t, unsigned short* __restrict__ W2t,
    unsigned short* __restrict__ W3t, unsigned short* __restrict__ W4t,
    unsigned short* __restrict__ Wct,
    unsigned short* __restrict__ xb, unsigned short* __restrict__ cmpl,
    float* __restrict__ stats, float* __restrict__ ent,
    unsigned int* __restrict__ bar,
    float* __restrict__ out)
{
    __shared__ short buf[32 * 256];   // 16 KB A/P tile (swizzled)
    __shared__ short Bs[256 * 32];    // 16 KB weight staging
    __shared__ float redS[256], redQ[256];
    __shared__ float tbl[512];
    __shared__ float went[4];

    const int tid  = threadIdx.x;
    const int wave = tid >> 6;
    const int lane = tid & 63;
    const int bid  = blockIdx.x;
    const int row0 = bid * 32;
    const int bcp  = (bid & (NCPY - 1)) * 512;

    unsigned int bgen = 0;
#define GSYNC() do { ++bgen; grid_sync_tree(bar, bgen * 16u, bid, tid); } while (0)

    // ---------- pre-sync: weight prep (blocks 0..135) + x col-stats (all) ----------
    if (bid < 136) {
        const int m = bid >> 3, kz = bid & 7, n = tid;
        const float* src; unsigned short* dst; int K;
        if (m == 0)      { src = W1f;                        dst = W1t;               K = 256; }
        else if (m == 1) { src = W2f;                        dst = W2t;               K = 128; }
        else if (m < 7)  { int i = m - 2;  src = W3f + (size_t)i * 128 * 256; dst = W3t + (size_t)i * 32768; K = 128; }
        else if (m < 12) { int i = m - 7;  src = W4f + (size_t)i * 128 * 256; dst = W4t + (size_t)i * 32768; K = 128; }
        else             { int i = m - 12; src = Wcf + (size_t)i * 64 * 256;  dst = Wct + (size_t)i * 16384; K = 64; }
        const int k0 = kz * 32;
        if (k0 < K)
            for (int k = k0; k < k0 + 32; ++k)
                dst[(size_t)n * K + k] = f2b(src[(size_t)k * 256 + n]);
    }
    {   // col stats of x for this block's 32 rows (buf reused as f32 scratch)
        float* red = (float*)buf;
        const int sub = wave;
        const int c4  = lane << 2;
        float s[4] = {0.f, 0.f, 0.f, 0.f}, q[4] = {0.f, 0.f, 0.f, 0.f};
#pragma unroll 8
        for (int i = 0; i < 8; ++i) {
            const int row = row0 + i * 4 + sub;
            float4 v = *(const float4*)(x + (size_t)row * 256 + c4);
            s[0] += v.x; q[0] += v.x * v.x;
            s[1] += v.y; q[1] += v.y * v.y;
            s[2] += v.z; q[2] += v.z * v.z;
            s[3] += v.w; q[3] += v.w * v.w;
        }
#pragma unroll
        for (int e = 0; e < 4; ++e) {
            red[sub * 512 + c4 + e] = s[e];
            red[sub * 512 + 256 + c4 + e] = q[e];
        }
        __syncthreads();
        float sS = red[tid] + red[512 + tid] + red[1024 + tid] + red[1536 + tid];
        float sQ = red[256 + tid] + red[768 + tid] + red[1280 + tid] + red[1792 + tid];
        atomicAdd(&stats[bcp + tid], sS);
        atomicAdd(&stats[bcp + 256 + tid], sQ);
    }
    GSYNC();

    // ---------- stage 0b: normalize x -> buf + xb + out ----------
    stage_B(Bs, W1t, 256, 0, wave, lane);   // chunk-0 of W1 for ni=0 stage-1
    {
        float s = 0.f, q = 0.f;
#pragma unroll
        for (int cp = 0; cp < NCPY; ++cp) {
            s += stats[cp * 512 + tid];
            q += stats[cp * 512 + 256 + tid];
        }
        float mean = s * INV_B, var = q * INV_B - mean * mean;
        float scl = enc_g[tid] * rsqrtf(var + BN_EPS);
        tbl[tid] = scl;
        tbl[256 + tid] = enc_b[tid] - mean * scl;
    }
    __syncthreads();
    {
        const int r = tid >> 3, cq = tid & 7;
        const size_t grow = (size_t)(row0 + r) * 256;
#pragma unroll
        for (int e = 0; e < 4; ++e) {
            const int c = cq * 32 + e * 8;
            float4 xa = *(const float4*)(x + grow + c);
            float4 xc = *(const float4*)(x + grow + c + 4);
            const float xv[8] = {xa.x, xa.y, xa.z, xa.w, xc.x, xc.y, xc.z, xc.w};
            float4 s0 = *(const float4*)&tbl[c], s1 = *(const float4*)&tbl[c + 4];
            float4 f0 = *(const float4*)&tbl[256 + c], f1 = *(const float4*)&tbl[256 + c + 4];
            const float sc[8] = {s0.x, s0.y, s0.z, s0.w, s1.x, s1.y, s1.z, s1.w};
            const float sh[8] = {f0.x, f0.y, f0.z, f0.w, f1.x, f1.y, f1.z, f1.w};
            float n[8];
            bf16x8 o8;
#pragma unroll
            for (int t = 0; t < 8; ++t) {
                n[t] = xv[t] * sc[t] + sh[t];
                o8[t] = (short)f2b(n[t]);
            }
            *(bf16x8*)((char*)buf + SWZ(r, c * 2)) = o8;
            *(bf16x8*)(xb + grow + c) = o8;
            if (c < OUTD) {
                float4 o1 = make_float4(5.f * fmaxf(n[0], 0.f), 5.f * fmaxf(n[1], 0.f),
                                        5.f * fmaxf(n[2], 0.f), 5.f * fmaxf(n[3], 0.f));
                float4 o2 = make_float4(5.f * fmaxf(n[4], 0.f), 5.f * fmaxf(n[5], 0.f),
                                        5.f * fmaxf(n[6], 0.f), 5.f * fmaxf(n[7], 0.f));
                *(float4*)(out + (size_t)(row0 + r) * OUTD + c) = o1;
                *(float4*)(out + (size_t)(row0 + r) * OUTD + c + 4) = o2;
            }
        }
    }

    // ---------- 5 iterations x 5 stages ----------
    // Next-stage chunk-0 weight DMA is issued BEFORE each GSYNC: the barrier's
    // entry __syncthreads drains it, so post-barrier GEMMs start with Bs hot.
    f32x4 acc[2][4];
    bf16x4 h[4];

    for (int ni = 0; ni < 5; ++ni) {
        float* s1 = stats + (size_t)(1 + ni * 5 + 0) * SLOT;
        float* s2 = stats + (size_t)(1 + ni * 5 + 1) * SLOT;
        float* s3 = stats + (size_t)(1 + ni * 5 + 2) * SLOT;
        float* s4 = stats + (size_t)(1 + ni * 5 + 3) * SLOT;
        float* s5 = stats + (size_t)(1 + ni * 5 + 4) * SLOT;

        // -- stage 1: (mask for ni>0) + GEMM vs W1t (K=256); W1t c0 pre-staged --
        if (ni > 0) {
            float* s5p = stats + (size_t)(1 + (ni - 1) * 5 + 4) * SLOT;
            build_tbl_mask(s5p, gc + (ni - 1) * 256, bc + (ni - 1) * 256, tid, tbl);
            if (ni == 1)
                mask_phase<0>(buf, tbl, xb, cmpl, ent, went, tid, wave, lane, row0, bid);
            else
                mask_phase<1>(buf, tbl, xb, cmpl, ent, went, tid, wave, lane, row0, bid);
        }
        gemm_core(buf, Bs, W1t, 256, wave, lane, acc);
        stage_epilogue(acc, buf, redS, redQ, s1, wave, lane, tid, bcp);
        stage_B(Bs, W2t, 128, 0, wave, lane);
        GSYNC();

        // -- stage 2: GLU(P1) -> GEMM vs W2t --
        build_tbl_glu(s1, g1, b1, 0, 128, tid, tbl);
        glu_prologue<128, false, true, 0>(buf, tbl, tid, 0, h);
        gemm_core(buf, Bs, W2t, 128, wave, lane, acc);
        stage_epilogue(acc, buf, redS, redQ, s2, wave, lane, tid, bcp);
        stage_B(Bs, W3t + (size_t)ni * 32768, 128, 0, wave, lane);
        GSYNC();

        // -- stage 3: GLU(P2)+res h1 -> GEMM vs W3t[ni] --
        build_tbl_glu(s2, g2, b2, 0, 128, tid, tbl);
        glu_prologue<128, true, true, 0>(buf, tbl, tid, 0, h);
        gemm_core(buf, Bs, W3t + (size_t)ni * 32768, 128, wave, lane, acc);
        stage_epilogue(acc, buf, redS, redQ, s3, wave, lane, tid, bcp);
        stage_B(Bs, W4t + (size_t)ni * 32768, 128, 0, wave, lane);
        GSYNC();

        // -- stage 4: GLU(P3)+res h2 -> GEMM vs W4t[ni] --
        build_tbl_glu(s3, g3 + ni * 256, b3 + ni * 256, 0, 128, tid, tbl);
        glu_prologue<128, true, true, 0>(buf, tbl, tid, 0, h);
        gemm_core(buf, Bs, W4t + (size_t)ni * 32768, 128, wave, lane, acc);
        stage_epilogue(acc, buf, redS, redQ, s4, wave, lane, tid, bcp);
        stage_B(Bs, Wct + (size_t)ni * 16384, 64, 0, wave, lane);
        GSYNC();

        // -- stage 5: fc = GLU(P4)[:,64:]+res h3[:,64:] -> GEMM vs Wct[ni] (K=64) --
        build_tbl_glu(s4, g4 + ni * 256, b4 + ni * 256, 64, 64, tid, tbl);
        glu_prologue<64, true, false, 2>(buf, tbl, tid, 64, h);
        gemm_core(buf, Bs, Wct + (size_t)ni * 16384, 64, wave, lane, acc);
        stage_epilogue(acc, buf, redS, redQ, s5, wave, lane, tid, bcp);
        if (ni < 4) stage_B(Bs, W1t, 256, 0, wave, lane);
        GSYNC();
    }

    // ---------- final: entropy of the last coef ----------
    build_tbl_mask(stats + (size_t)(1 + 4 * 5 + 4) * SLOT,
                   gc + 4 * 256, bc + 4 * 256, tid, tbl);
    mask_phase<2>(buf, tbl, xb, cmpl, ent, went, tid, wave, lane, row0, bid);
    GSYNC();

    if (bid == 0 && wave == 0) {
        float v = 0.f;
#pragma unroll
        for (int i = 0; i < 4; ++i) v += ent[(lane + 64 * i) << 5];
        v = waveSumAll(v);
        if (lane == 0) out[(size_t)BSZ * OUTD] = v;
    }
#undef GSYNC
}

// ======================= FALLBACK PATH (proven R2 pipeline) =======================
__global__ __launch_bounds__(256) void prep_w(
    const float* __restrict__ W1, const float* __restrict__ W2,
    const float* __restrict__ W3, const float* __restrict__ W4,
    const float* __restrict__ Wc,
    unsigned short* __restrict__ W1t, unsigned short* __restrict__ W2t,
    unsigned short* __restrict__ W3t, unsigned short* __restrict__ W4t,
    unsigned short* __restrict__ Wct)
{
    const int m = blockIdx.x, kz = blockIdx.y, n = threadIdx.x;
    const float* src; unsigned short* dst; int K;
    if (m == 0)      { src = W1;                        dst = W1t;               K = 256; }
    else if (m == 1) { src = W2;                        dst = W2t;               K = 128; }
    else if (m < 7)  { int i = m - 2;  src = W3 + (size_t)i * 128 * 256; dst = W3t + (size_t)i * 32768; K = 128; }
    else if (m < 12) { int i = m - 7;  src = W4 + (size_t)i * 128 * 256; dst = W4t + (size_t)i * 32768; K = 128; }
    else             { int i = m - 12; src = Wc + (size_t)i * 64 * 256;  dst = Wct + (size_t)i * 16384; K = 64; }
    const int k0 = kz * 32;
    if (k0 >= K) return;
    for (int k = k0; k < k0 + 32; ++k)
        dst[(size_t)n * K + k] = f2b(src[(size_t)k * 256 + n]);
}

__global__ __launch_bounds__(256) void colstats(const float* __restrict__ X,
                                                float* __restrict__ st0) {
    __shared__ float red[4][512];
    const int sub = threadIdx.x >> 6;
    const int c4  = (threadIdx.x & 63) << 2;
    float s[4] = {0.f, 0.f, 0.f, 0.f}, q[4] = {0.f, 0.f, 0.f, 0.f};
#pragma unroll 8
    for (int i = 0; i < 8; ++i) {
        const int row = blockIdx.x * 32 + i * 4 + sub;
        float4 v = *(const float4*)(X + (size_t)row * 256 + c4);
        s[0] += v.x; q[0] += v.x * v.x;
        s[1] += v.y; q[1] += v.y * v.y;
        s[2] += v.z; q[2] += v.z * v.z;
        s[3] += v.w; q[3] += v.w * v.w;
    }
#pragma unroll
    for (int e = 0; e < 4; ++e) {
        red[sub][c4 + e] = s[e];
        red[sub][256 + c4 + e] = q[e];
    }
    __syncthreads();
    const int t = threadIdx.x;
    const int cp = (blockIdx.x & (NCPY - 1)) * 512;
    float sS = red[0][t] + red[1][t] + red[2][t] + red[3][t];
    float sQ = red[0][256 + t] + red[1][256 + t] + red[2][256 + t] + red[3][256 + t];
    atomicAdd(&st0[cp + t], sS);
    atomicAdd(&st0[cp + 256 + t], sQ);
}

__global__ __launch_bounds__(256) void norm_x(const float* __restrict__ x,
                                              const float* __restrict__ st0,
                                              const float* __restrict__ g,
                                              const float* __restrict__ b,
                                              unsigned short* __restrict__ xb,
                                              float* __restrict__ out) {
    const int i4 = blockIdx.x * 256 + threadIdx.x;
    const int row = i4 >> 6, c4 = (i4 & 63) << 2;
    float4 xv = *(const float4*)(x + (size_t)row * 256 + c4);
    float sS[4] = {0.f, 0.f, 0.f, 0.f}, sQ[4] = {0.f, 0.f, 0.f, 0.f};
#pragma unroll
    for (int cp = 0; cp < NCPY; ++cp) {
        float4 a = *(const float4*)&st0[cp * 512 + c4];
        float4 q = *(const float4*)&st0[cp * 512 + 256 + c4];
        sS[0] += a.x; sS[1] += a.y; sS[2] += a.z; sS[3] += a.w;
        sQ[0] += q.x; sQ[1] += q.y; sQ[2] += q.z; sQ[3] += q.w;
    }
    float4 gv = *(const float4*)&g[c4];
    float4 bv = *(const float4*)&b[c4];
    const float* xp = (const float*)&xv;
    const float* gp = (const float*)&gv; const float* bp = (const float*)&bv;
    float n[4];
    ushort4 ob;
    unsigned short* obp = (unsigned short*)&ob;
#pragma unroll
    for (int e = 0; e < 4; ++e) {
        float mean = sS[e] * INV_B;
        float var  = sQ[e] * INV_B - mean * mean;
        float sc   = gp[e] * rsqrtf(var + BN_EPS);
        float sh   = bp[e] - mean * sc;
        n[e] = xp[e] * sc + sh;
        obp[e] = f2b(n[e]);
    }
    *(ushort4*)(xb + (size_t)row * 256 + c4) = ob;
    if (c4 < OUTD) {
        float4 ov = make_float4(5.0f * fmaxf(n[0], 0.f), 5.0f * fmaxf(n[1], 0.f),
                                5.0f * fmaxf(n[2], 0.f), 5.0f * fmaxf(n[3], 0.f));
        *(float4*)(out + (size_t)row * OUTD + c4) = ov;
    }
}

__device__ __forceinline__ void gemm_epilogue(
    f32x4 (&acc)[2][4], int row0, int wave, int lane, int tid, int bcp,
    float* redS, float* redQ,
    unsigned short* __restrict__ Pout, float* __restrict__ statsOut)
{
    const int fm = lane & 15;
    const int orow = row0 + (lane >> 4) * 4;
    const int ocol = wave * 64 + fm;
#pragma unroll
    for (int i = 0; i < 2; ++i)
#pragma unroll
        for (int j = 0; j < 4; ++j)
#pragma unroll
            for (int r = 0; r < 4; ++r)
                Pout[(size_t)(orow + i * 16 + r) * 256 + (ocol + j * 16)] = f2b(acc[i][j][r]);

#pragma unroll
    for (int j = 0; j < 4; ++j) {
        float s = 0.f, q = 0.f;
#pragma unroll
        for (int i = 0; i < 2; ++i)
#pragma unroll
            for (int r = 0; r < 4; ++r) {
                float v = acc[i][j][r];
                s += v; q += v * v;
            }
        s += __shfl_xor(s, 16, 64); s += __shfl_xor(s, 32, 64);
        q += __shfl_xor(q, 16, 64); q += __shfl_xor(q, 32, 64);
        if (lane < 16) {
            redS[wave * 64 + j * 16 + lane] = s;
            redQ[wave * 64 + j * 16 + lane] = q;
        }
    }
    __syncthreads();
    atomicAdd(&statsOut[bcp + tid], redS[tid]);
    atomicAdd(&statsOut[bcp + 256 + tid], redQ[tid]);
}

__global__ __launch_bounds__(256) void gemm_bf16(
    const unsigned short* __restrict__ A,
    const unsigned short* __restrict__ Wt, int K,
    unsigned short* __restrict__ P,
    float* __restrict__ statsOut)
{
    __shared__ short As[32 * 32];
    __shared__ short Bs[256 * 32];
    __shared__ float redS[256], redQ[256];

    const int tid  = threadIdx.x;
    const int wave = tid >> 6;
    const int lane = tid & 63;
    const int row0 = blockIdx.x * 32;
    const int bcp  = (blockIdx.x & (NCPY - 1)) * 512;

    const int sr = lane >> 2;
    const int sc = (lane & 3) * 8;
    const int fm = lane & 15;
    const int fq = (lane >> 4) * 8;

    f32x4 acc[2][4];
#pragma unroll
    for (int i = 0; i < 2; ++i)
#pragma unroll
        for (int j = 0; j < 4; ++j)
            acc[i][j] = (f32x4){0.f, 0.f, 0.f, 0.f};

    for (int k0 = 0; k0 < K; k0 += 32) {
        if (wave < 2)
            async16(A + (size_t)(row0 + wave * 16 + sr) * K + k0 + sc,
                    (void*)(As + wave * 512 + lane * 8));
#pragma unroll
        for (int t = 0; t < 4; ++t) {
            const int wr = wave * 64 + t * 16 + sr;
            async16(Wt + (size_t)wr * K + k0 + sc,
                    (void*)(Bs + (wave * 4 + t) * 512 + lane * 8));
        }
        __syncthreads();

        bf16x8 af[2], bfr[4];
#pragma unroll
        for (int i = 0; i < 2; ++i)
            af[i] = *(const bf16x8*)(As + (i * 16 + fm) * 32 + fq);
#pragma unroll
        for (int j = 0; j < 4; ++j)
            bfr[j] = *(const bf16x8*)(Bs + (wave * 64 + j * 16 + fm) * 32 + fq);
#pragma unroll
        for (int i = 0; i < 2; ++i)
#pragma unroll
            for (int j = 0; j < 4; ++j)
                acc[i][j] = __builtin_amdgcn_mfma_f32_16x16x32_bf16(af[i], bfr[j], acc[i][j], 0, 0, 0);
        __syncthreads();
    }

    gemm_epilogue(acc, row0, wave, lane, tid, bcp, redS, redQ, P, statsOut);
}

template <int MODE>
__global__ __launch_bounds__(256) void gemm_mask(
    const unsigned short* Pc,
    const float* __restrict__ cstats,
    const float* __restrict__ gc, const float* __restrict__ bc,
    const unsigned short* __restrict__ xb,
    unsigned short* __restrict__ cmpl,
    float* __restrict__ ent,
    const unsigned short* __restrict__ Wt,
    unsigned short* Pout,
    float* __restrict__ statsOut)
{
    __shared__ short Am[32 * 256];
    __shared__ short Bs[256 * 32];
    __shared__ float redS[256], redQ[256];
    __shared__ float tScl[256], tShf[256];
    __shared__ float went[4];

    const int tid  = threadIdx.x;
    const int wave = tid >> 6;
    const int lane = tid & 63;
    const int row0 = blockIdx.x * 32;
    const int bcp  = (blockIdx.x & (NCPY - 1)) * 512;

    const int sr = lane >> 2;
    const int sc = (lane & 3) * 8;

#pragma unroll
    for (int t = 0; t < 4; ++t) {
        const int wr = wave * 64 + t * 16 + sr;
        async16(Wt + (size_t)wr * 256 + sc,
                (void*)(Bs + (wave * 4 + t) * 512 + lane * 8));
    }

    {
        float s = 0.f, q = 0.f;
#pragma unroll
        for (int cp = 0; cp < NCPY; ++cp) {
            s += cstats[cp * 512 + tid];
            q += cstats[cp * 512 + 256 + tid];
        }
        float mean = s * INV_B, var = q * INV_B - mean * mean;
        float scl_ = gc[tid] * rsqrtf(var + BN_EPS);
        tScl[tid] = scl_;
        tShf[tid] = bc[tid] - mean * scl_;
    }
    __syncthreads();

    const int r  = tid >> 3;
    const int cq = tid & 7;
    const size_t grow = (size_t)(row0 + r) * 256;

    float l[32];
    float mx = -1e30f;
#pragma unroll
    for (int e = 0; e < 4; ++e) {
        const int c = cq * 32 + e * 8;
        bf16x8 pv = *(const bf16x8*)(Pc + grow + c);
        bf16x8 cv;
        if (MODE) cv = *(const bf16x8*)(cmpl + grow + c);
        float4 s0 = *(const float4*)&tScl[c], s1 = *(const float4*)&tScl[c + 4];
        float4 h0 = *(const float4*)&tShf[c], h1 = *(const float4*)&tShf[c + 4];
        const float* sp0 = (const float*)&s0; const float* sp1 = (const float*)&s1;
        const float* hp0 = (const float*)&h0; const float* hp1 = (const float*)&h1;
#pragma unroll
        for (int t = 0; t < 8; ++t) {
            float scl_ = (t < 4) ? sp0[t] : sp1[t - 4];
            float shf_ = (t < 4) ? hp0[t] : hp1[t - 4];
            float cl = MODE ? b2f((unsigned short)cv[t]) : 1.0f;
            float v = (b2f((unsigned short)pv[t]) * scl_ + shf_) * cl;
            l[e * 8 + t] = v;
            mx = fmaxf(mx, v);
        }
    }
    mx = fmaxf(mx, __shfl_xor(mx, 1, 64));
    mx = fmaxf(mx, __shfl_xor(mx, 2, 64));
    mx = fmaxf(mx, __shfl_xor(mx, 4, 64));

    float ssum = 0.f;
#pragma unroll
    for (int i = 0; i < 32; ++i) { l[i] = __expf(l[i] - mx); ssum += l[i]; }
    ssum += __shfl_xor(ssum, 1, 64);
    ssum += __shfl_xor(ssum, 2, 64);
    ssum += __shfl_xor(ssum, 4, 64);
    const float inv = 1.0f / ssum;

    float et = 0.f;
#pragma unroll
    for (int e = 0; e < 4; ++e) {
        const int c = cq * 32 + e * 8;
        bf16x8 xv = *(const bf16x8*)(xb + grow + c);
        bf16x8 cv2;
        if (MODE) cv2 = *(const bf16x8*)(cmpl + grow + c);
        bf16x8 mo, co;
#pragma unroll
        for (int t = 0; t < 8; ++t) {
            float m = l[e * 8 + t] * inv;
            et -= m * __logf(m + SM_EPS);
            float cl = MODE ? b2f((unsigned short)cv2[t]) : 1.0f;
            co[t] = (short)f2b(cl * (1.5f - m));
            mo[t] = (short)f2b(m * b2f((unsigned short)xv[t]));
        }
        *(bf16x8*)(cmpl + grow + c) = co;
        unsigned int byte = (unsigned int)(r * 512 + c * 2);
        byte ^= ((unsigned int)(r & 7)) << 4;
        *(bf16x8*)((char*)Am + byte) = mo;
    }
    et += __shfl_xor(et, 1, 64);
    et += __shfl_xor(et, 2, 64);
    et += __shfl_xor(et, 4, 64);
    float wet = waveSumAll(et) * 0.125f;
    if (lane == 0) went[wave] = wet;
    __syncthreads();
    if (tid == 0) {
        float v = went[0] + went[1] + went[2] + went[3];
        atomicAdd(&ent[(blockIdx.x & 255) << 5], v * (INV_B * 0.2f));
    }

    const int fm = lane & 15;
    const int fq = (lane >> 4) * 8;

    f32x4 acc[2][4];
#pragma unroll
    for (int i = 0; i < 2; ++i)
#pragma unroll
        for (int j = 0; j < 4; ++j)
            acc[i][j] = (f32x4){0.f, 0.f, 0.f, 0.f};

    for (int k0 = 0; k0 < 256; k0 += 32) {
        bf16x8 af[2], bfr[4];
#pragma unroll
        for (int i = 0; i < 2; ++i) {
            const int row = i * 16 + fm;
            unsigned int byte = (unsigned int)(row * 512 + (k0 + fq) * 2);
            byte ^= ((unsigned int)(row & 7)) << 4;
            af[i] = *(const bf16x8*)((const char*)Am + byte);
        }
#pragma unroll
        for (int j = 0; j < 4; ++j)
            bfr[j] = *(const bf16x8*)(Bs + (wave * 64 + j * 16 + fm) * 32 + fq);
#pragma unroll
        for (int i = 0; i < 2; ++i)
#pragma unroll
            for (int j = 0; j < 4; ++j)
                acc[i][j] = __builtin_amdgcn_mfma_f32_16x16x32_bf16(af[i], bfr[j], acc[i][j], 0, 0, 0);
        __syncthreads();
        if (k0 + 32 < 256) {
#pragma unroll
            for (int t = 0; t < 4; ++t) {
                const int wr = wave * 64 + t * 16 + sr;
                async16(Wt + (size_t)wr * 256 + (k0 + 32) + sc,
                        (void*)(Bs + (wave * 4 + t) * 512 + lane * 8));
            }
            __syncthreads();
        }
    }

    gemm_epilogue(acc, row0, wave, lane, tid, bcp, redS, redQ, Pout, statsOut);
}

template <bool RES, bool WRITE_H>
__global__ __launch_bounds__(256) void gemm_glu(
    const unsigned short* __restrict__ Pprev,
    const float* __restrict__ pstats,
    const float* __restrict__ pg,
    const float* __restrict__ pb,
    const unsigned short* __restrict__ res,
    int colOff,
    const unsigned short* __restrict__ Wt, int K,
    unsigned short* __restrict__ Pout,
    float* __restrict__ statsOut,
    unsigned short* __restrict__ hOut)
{
    __shared__ short As[32 * 32];
    __shared__ short Bs[256 * 32];
    __shared__ float redS[256], redQ[256];
    __shared__ float tScA[128], tShA[128], tScG[128], tShG[128];

    const int tid  = threadIdx.x;
    const int wave = tid >> 6;
    const int lane = tid & 63;
    const int row0 = blockIdx.x * 32;
    const int bcp  = (blockIdx.x & (NCPY - 1)) * 512;

    if (tid < K) {
        const int ch = colOff + tid;
        const int cg = ch + 128;
        float sA = 0.f, qA = 0.f, sG = 0.f, qG = 0.f;
#pragma unroll
        for (int cp = 0; cp < NCPY; ++cp) {
            const float* p = pstats + cp * 512;
            sA += p[ch]; qA += p[256 + ch];
            sG += p[cg]; qG += p[256 + cg];
        }
        float ma = sA * INV_B, va = qA * INV_B - ma * ma;
        float scA = pg[ch] * rsqrtf(va + BN_EPS);
        tScA[tid] = scA; tShA[tid] = pb[ch] - ma * scA;
        float mg = sG * INV_B, vg = qG * INV_B - mg * mg;
        float scG = pg[cg] * rsqrtf(vg + BN_EPS);
        tScG[tid] = scG; tShG[tid] = pb[cg] - mg * scG;
    }
    __syncthreads();

    const int sr = lane >> 2;
    const int sc = (lane & 3) * 8;
    const int ar = tid >> 3;
    const int ac = (tid & 7) * 4;
    const int fm = lane & 15;
    const int fq = (lane >> 4) * 8;

    f32x4 acc[2][4];
#pragma unroll
    for (int i = 0; i < 2; ++i)
#pragma unroll
        for (int j = 0; j < 4; ++j)
            acc[i][j] = (f32x4){0.f, 0.f, 0.f, 0.f};

    for (int k0 = 0; k0 < K; k0 += 32) {
#pragma unroll
        for (int t = 0; t < 4; ++t) {
            const int wr = wave * 64 + t * 16 + sr;
            async16(Wt + (size_t)wr * K + k0 + sc,
                    (void*)(Bs + (wave * 4 + t) * 512 + lane * 8));
        }

        {
            const int kk = k0 + ac;
            const size_t grow = (size_t)(row0 + ar);

            bf16x4 lo = *(const bf16x4*)(Pprev + grow * 256 + colOff + kk);
            bf16x4 hi = *(const bf16x4*)(Pprev + grow * 256 + colOff + kk + 128);
            bf16x4 rv;
            if (RES) rv = *(const bf16x4*)(res + grow * 128 + kk);

            float4 a0 = *(const float4*)&tScA[kk];
            float4 h0 = *(const float4*)&tShA[kk];
            float4 g0 = *(const float4*)&tScG[kk];
            float4 s0 = *(const float4*)&tShG[kk];
            float scA[4] = {a0.x, a0.y, a0.z, a0.w};
            float shA[4] = {h0.x, h0.y, h0.z, h0.w};
            float scG[4] = {g0.x, g0.y, g0.z, g0.w};
            float shG[4] = {s0.x, s0.y, s0.z, s0.w};

            bf16x4 o4;
#pragma unroll
            for (int e = 0; e < 4; ++e) {
                float na = b2f((unsigned short)lo[e]) * scA[e] + shA[e];
                float ng = b2f((unsigned short)hi[e]) * scG[e] + shG[e];
                float v = na * (1.0f / (1.0f + __expf(-ng)));
                if (RES) v = (v + b2f((unsigned short)rv[e])) * SQRT_HALF;
                o4[e] = (short)f2b(v);
            }
            *(bf16x4*)(As + ar * 32 + ac) = o4;
            if (WRITE_H)
                *(bf16x4*)(hOut + grow * 128 + kk) = o4;
        }
        __syncthreads();

        bf16x8 af[2], bfr[4];
#pragma unroll
        for (int i = 0; i < 2; ++i)
            af[i] = *(const bf16x8*)(As + (i * 16 + fm) * 32 + fq);
#pragma unroll
        for (int j = 0; j < 4; ++j)
            bfr[j] = *(const bf16x8*)(Bs + (wave * 64 + j * 16 + fm) * 32 + fq);
#pragma unroll
        for (int i = 0; i < 2; ++i)
#pragma unroll
            for (int j = 0; j < 4; ++j)
                acc[i][j] = __builtin_amdgcn_mfma_f32_16x16x32_bf16(af[i], bfr[j], acc[i][j], 0, 0, 0);
        __syncthreads();
    }

    gemm_epilogue(acc, row0, wave, lane, tid, bcp, redS, redQ, Pout, statsOut);
}

__global__ __launch_bounds__(256) void coef_ent(const unsigned short* __restrict__ Pc,
                                                const float* __restrict__ stats,
                                                const float* __restrict__ gc,
                                                const float* __restrict__ bc,
                                                const unsigned short* __restrict__ cmpl,
                                                float* __restrict__ ent) {
    const int w    = threadIdx.x >> 6;
    const int lane = threadIdx.x & 63;
    const int row  = blockIdx.x * 4 + w;
    const int c    = lane << 2;
    __shared__ float went[4];

    float sS[4] = {0.f, 0.f, 0.f, 0.f}, sQ[4] = {0.f, 0.f, 0.f, 0.f};
#pragma unroll
    for (int cp = 0; cp < NCPY; ++cp) {
        float4 a = *(const float4*)&stats[cp * 512 + c];
        float4 q = *(const float4*)&stats[cp * 512 + 256 + c];
        sS[0] += a.x; sS[1] += a.y; sS[2] += a.z; sS[3] += a.w;
        sQ[0] += q.x; sQ[1] += q.y; sQ[2] += q.z; sQ[3] += q.w;
    }
    float4 gv = *(const float4*)&gc[c];
    float4 bv = *(const float4*)&bc[c];
    const float* gvv = (const float*)&gv; const float* bvv = (const float*)&bv;

    float scl[4], shf[4];
#pragma unroll
    for (int e = 0; e < 4; ++e) {
        float mean = sS[e] * INV_B, var = sQ[e] * INV_B - mean * mean;
        scl[e] = gvv[e] * rsqrtf(var + BN_EPS);
        shf[e] = bvv[e] - mean * scl[e];
    }

    const size_t idx = (size_t)row * 256 + c;
    ushort4 pu = *(const ushort4*)(Pc + idx);
    const unsigned short* puv = (const unsigned short*)&pu;
    ushort4 cu = *(const ushort4*)(cmpl + idx);
    const unsigned short* cuv = (const unsigned short*)&cu;

    float l[4];
#pragma unroll
    for (int e = 0; e < 4; ++e)
        l[e] = (b2f(puv[e]) * scl[e] + shf[e]) * b2f(cuv[e]);

    float mx = waveMaxAll(fmaxf(fmaxf(l[0], l[1]), fmaxf(l[2], l[3])));
    float e0 = __expf(l[0] - mx), e1 = __expf(l[1] - mx),
          e2 = __expf(l[2] - mx), e3 = __expf(l[3] - mx);
    float inv = 1.0f / waveSumAll(e0 + e1 + e2 + e3);

    float m[4] = {e0 * inv, e1 * inv, e2 * inv, e3 * inv};

    float et = -m[0] * __logf(m[0] + SM_EPS) - m[1] * __logf(m[1] + SM_EPS)
             - m[2] * __logf(m[2] + SM_EPS) - m[3] * __logf(m[3] + SM_EPS);
    et = waveSumAll(et);
    if (lane == 0) went[w] = et;
    __syncthreads();
    if (threadIdx.x == 0) {
        float v = went[0] + went[1] + went[2] + went[3];
        atomicAdd(&ent[(blockIdx.x & 255) << 5], v * (INV_B * 0.2f));
    }
}

__global__ __launch_bounds__(64) void write_ent(const float* __restrict__ ent,
                                                float* __restrict__ dst) {
    const int lane = threadIdx.x;
    float v = 0.f;
#pragma unroll
    for (int i = 0; i < 4; ++i) v += ent[(lane + 64 * i) << 5];
    v = waveSumAll(v);
    if (lane == 0) dst[0] = v;
}

// ---------------- host orchestration ----------------
extern "C" void kernel_launch(void* const* d_in, const int* in_sizes, int n_in,
                              void* d_out, int out_size, void* d_ws, size_t ws_size,
                              hipStream_t stream) {
    const float* x     = (const float*)d_in[0];
    const float* enc_g = (const float*)d_in[1];
    const float* enc_b = (const float*)d_in[2];
    const float* W1 = (const float*)d_in[3];
    const float* g1 = (const float*)d_in[4];
    const float* b1 = (const float*)d_in[5];
    const float* W2 = (const float*)d_in[6];
    const float* g2 = (const float*)d_in[7];
    const float* b2 = (const float*)d_in[8];
    const float* W3 = (const float*)d_in[9];
    const float* g3 = (const float*)d_in[10];
    const float* b3 = (const float*)d_in[11];
    const float* W4 = (const float*)d_in[12];
    const float* g4 = (const float*)d_in[13];
    const float* b4 = (const float*)d_in[14];
    const float* Wc = (const float*)d_in[15];
    const float* gc = (const float*)d_in[16];
    const float* bc = (const float*)d_in[17];
    float* out = (float*)d_out;

    const size_t NBF = (size_t)BSZ * FDIM;
    const size_t NBH = (size_t)BSZ * HDIM;

    unsigned short* xb     = (unsigned short*)d_ws;
    unsigned short* masked = xb + NBF;            // fallback ping buffer; mega: bar lives here
    unsigned short* Pb1    = masked + NBF;
    unsigned short* h1     = Pb1 + NBF;
    unsigned short* h2     = h1 + NBH;
    unsigned short* h3     = h2 + NBH;
    unsigned short* cmpl   = h3 + NBH;
    unsigned short* W1t    = cmpl + NBF;
    unsigned short* W2t    = W1t + 65536;
    unsigned short* W3t    = W2t + 32768;
    unsigned short* W4t    = W3t + 163840;
    unsigned short* Wct    = W4t + 163840;
    float* stats = (float*)(Wct + 81920);
    float* ent   = stats + 26 * SLOT;
    unsigned int* bar = (unsigned int*)masked;    // 64 counters x 128B = 8KB, mega only

    unsigned short* Pb2 = masked;

    // one-time occupancy check (host-side query; capture-safe)
    static int s_ok = -1;
    if (s_ok < 0) {
        int occ = 0, mpc = 0, dev = 0;
        hipGetDevice(&dev);
        hipDeviceProp_t prop;
        if (hipGetDeviceProperties(&prop, dev) == hipSuccess) mpc = prop.multiProcessorCount;
        if (hipOccupancyMaxActiveBlocksPerMultiprocessor(
                &occ, reinterpret_cast<const void*>(mega), 256, 0) != hipSuccess) occ = 0;
        s_ok = (occ >= 4 && occ * mpc >= GRID) ? 1 : 0;
    }

    hipMemsetAsync(stats, 0, (26 * SLOT + 256 * 32) * sizeof(float), stream);

    if (s_ok) {
        hipMemsetAsync(bar, 0, 64 * 32 * sizeof(unsigned int), stream);
        mega<<<GRID, 256, 0, stream>>>(
            x, enc_g, enc_b, g1, b1, g2, b2, g3, b3, g4, b4, gc, bc,
            W1, W2, W3, W4, Wc, W1t, W2t, W3t, W4t, Wct,
            xb, cmpl, stats, ent, bar, out);
        return;
    }

    // -------- fallback: proven multi-kernel pipeline --------
    prep_w<<<dim3(17, 8), 256, 0, stream>>>(W1, W2, W3, W4, Wc, W1t, W2t, W3t, W4t, Wct);
    colstats<<<1024, 256, 0, stream>>>(x, stats);
    norm_x<<<8192, 256, 0, stream>>>(x, stats, enc_g, enc_b, xb, out);

    for (int ni = 0; ni < 5; ++ni) {
        float* s1 = stats + (size_t)(1 + ni * 5 + 0) * SLOT;
        float* s2 = stats + (size_t)(1 + ni * 5 + 1) * SLOT;
        float* s3 = stats + (size_t)(1 + ni * 5 + 2) * SLOT;
        float* s4 = stats + (size_t)(1 + ni * 5 + 3) * SLOT;
        float* s5 = stats + (size_t)(1 + ni * 5 + 4) * SLOT;

        if (ni == 0) {
            gemm_bf16<<<1024, 256, 0, stream>>>(xb, W1t, 256, Pb1, s1);
        } else {
            float* s5p = stats + (size_t)(1 + (ni - 1) * 5 + 4) * SLOT;
            if (ni == 1)
                gemm_mask<0><<<1024, 256, 0, stream>>>(
                    Pb1, s5p, gc, bc, xb, cmpl, ent, W1t, Pb1, s1);
            else
                gemm_mask<1><<<1024, 256, 0, stream>>>(
                    Pb1, s5p, gc + (ni - 1) * 256, bc + (ni - 1) * 256,
                    xb, cmpl, ent, W1t, Pb1, s1);
        }

        gemm_glu<false, true><<<1024, 256, 0, stream>>>(
            Pb1, s1, g1, b1, nullptr, 0, W2t, 128, Pb2, s2, h1);
        gemm_glu<true, true><<<1024, 256, 0, stream>>>(
            Pb2, s2, g2, b2, h1, 0, W3t + (size_t)ni * 32768, 128, Pb1, s3, h2);
        gemm_glu<true, true><<<1024, 256, 0, stream>>>(
            Pb1, s3, g3 + ni * 256, b3 + ni * 256, h2, 0,
            W4t + (size_t)ni * 32768, 128, Pb2, s4, h3);
        gemm_glu<true, false><<<1024, 256, 0, stream>>>(
            Pb2, s4, g4 + ni * 256, b4 + ni * 256, h3 + 64, 64,
            Wct + (size_t)ni * 16384, 64, Pb1, s5, nullptr);
    }

    coef_ent<<<BSZ / 4, 256, 0, stream>>>(
        Pb1, stats + (size_t)(1 + 4 * 5 + 4) * SLOT,
        gc + 4 * 256, bc + 4 * 256, cmpl, ent);

    write_ent<<<1, 64, 0, stream>>>(ent, out + (size_t)BSZ * OUTD);
}

// Round 7
// 556.920 us; speedup vs baseline: 1.0155x; 1.0059x over previous
//
#include <hip/hip_runtime.h>
#include <math.h>

#define BSZ   32768
#define FDIM  256
#define HDIM  128
#define OUTD  64
#define SQRT_HALF 0.70710678118654752f
#define BN_EPS 1e-5f
#define SM_EPS 1e-5f
#define INV_B (1.0f / 32768.0f)
#define NCPY  8
#define SLOT  (NCPY * 512)
#define GRID  1024

// swizzled byte offset inside the 32x256 bf16 tile (row-major, 512 B rows)
#define SWZ(r, cb) ((((r) << 9) + (cb)) ^ (((r) & 7) << 4))

typedef __attribute__((ext_vector_type(8))) short bf16x8;
typedef __attribute__((ext_vector_type(4))) short bf16x4;
typedef __attribute__((ext_vector_type(4))) float f32x4;

__device__ __forceinline__ float b2f(unsigned short u) {
    return __uint_as_float(((unsigned int)u) << 16);
}
__device__ __forceinline__ unsigned short f2b(float f) {
    unsigned int u = __float_as_uint(f);
    u += 0x7fff + ((u >> 16) & 1);   // RNE
    return (unsigned short)(u >> 16);
}

__device__ __forceinline__ void async16(const void* g, void* l) {
    __builtin_amdgcn_global_load_lds(
        (const __attribute__((address_space(1))) void*)(uintptr_t)g,
        (__attribute__((address_space(3))) void*)(unsigned int)(uintptr_t)l,
        16, 0, 0);
}

__device__ inline float waveMaxAll(float v) {
#pragma unroll
    for (int m = 32; m > 0; m >>= 1) v = fmaxf(v, __shfl_xor(v, m, 64));
    return v;
}
__device__ inline float waveSumAll(float v) {
#pragma unroll
    for (int m = 32; m > 0; m >>= 1) v += __shfl_xor(v, m, 64);
    return v;
}

// ---- leader-release grid barrier ----
// arr: 64 monotonic arrival counters (one 128B line each) + rel word at
// arr[64*32] (own line). Arrivals spread over 64 lines (16 blocks each).
// ONLY block 0 polls the arrival lines; it release-stores rel = gen.
// All other blocks poll the single read-only rel line with ONE lane.
// This cuts barrier polling traffic ~64x vs all-blocks-poll-64-lines.
__device__ __forceinline__ void grid_sync_lr(unsigned int* arr, unsigned int* rel,
                                             unsigned int gen, int bid, int tid) {
    __syncthreads();                 // block quiesced (drains vmcnt/lgkmcnt)
    if (tid == 0) {
        __threadfence();             // release: prior global writes visible
        __hip_atomic_fetch_add(&arr[(bid & 63) << 5], 1u,
                               __ATOMIC_RELEASE, __HIP_MEMORY_SCOPE_AGENT);
    }
    if (bid == 0) {
        if (tid < 64) {
            unsigned int* p = &arr[tid << 5];
            long spin = 0;
            while (__hip_atomic_load(p, __ATOMIC_ACQUIRE, __HIP_MEMORY_SCOPE_AGENT) < gen * 16u) {
                if (++spin > (1L << 24)) break;   // fail loud, not hung
                __builtin_amdgcn_s_sleep(1);
            }
            __threadfence();         // acquire: invalidate stale cache
        }
        __syncthreads();
        if (tid == 0)
            __hip_atomic_store(rel, gen, __ATOMIC_RELEASE, __HIP_MEMORY_SCOPE_AGENT);
    } else {
        if (tid == 0) {
            long spin = 0;
            while (__hip_atomic_load(rel, __ATOMIC_ACQUIRE, __HIP_MEMORY_SCOPE_AGENT) < gen) {
                if (++spin > (1L << 24)) break;
                __builtin_amdgcn_s_sleep(2);
            }
            __threadfence();         // acquire: invalidate stale cache
        }
    }
    __syncthreads();
}

// ---- B-tile staging: one 256x32 k-chunk of Wt into Bs ----
// NOTE: wave w writes exactly rows [64w, 64w+64) of Bs and the MFMA phase
// reads exactly those rows -> Bs is wave-private; no block barrier needed.
__device__ __forceinline__ void stage_B(short* Bs, const unsigned short* __restrict__ Wt,
                                        int K, int k0, int wave, int lane) {
    const int sr = lane >> 2;
    const int sc = (lane & 3) * 8;
#pragma unroll
    for (int t = 0; t < 4; ++t) {
        const int wr = wave * 64 + t * 16 + sr;
        async16(Wt + (size_t)wr * K + k0 + sc, (void*)(Bs + (wave * 4 + t) * 512 + lane * 8));
    }
}

// ---- GEMM core: A (32x256 bf16, swizzled) from buf, B staged per k-step ----
// CONTRACT: caller already issued stage_B(..., k0=0) (same wave).
// Wave-decoupled: buf is read-only during the loop; Bs is wave-private.
// Per chunk: vmcnt(0) (own DMAs done) -> ds_read -> MFMA -> lgkmcnt(0) ->
// issue next chunk DMA. Entry barrier: buf ready. Exit barrier: all waves
// done reading buf (caller may overwrite).
__device__ __forceinline__ void gemm_core(const short* buf, short* Bs,
                                          const unsigned short* __restrict__ Wt, int K,
                                          int wave, int lane, f32x4 (&acc)[2][4]) {
    const int fm = lane & 15;
    const int fq = (lane >> 4) * 8;
#pragma unroll
    for (int i = 0; i < 2; ++i)
#pragma unroll
        for (int j = 0; j < 4; ++j)
            acc[i][j] = (f32x4){0.f, 0.f, 0.f, 0.f};

    __syncthreads();   // buf writes from all waves visible; entry DMA drained? no —
                       // (entry barrier's implicit vmcnt(0) also drains chunk-0 DMA)

    for (int k0 = 0; k0 < K; k0 += 32) {
        asm volatile("s_waitcnt vmcnt(0)" ::: "memory");   // this wave's chunk DMAs done
        bf16x8 af[2], bfr[4];
#pragma unroll
        for (int i = 0; i < 2; ++i)
            af[i] = *(const bf16x8*)((const char*)buf + SWZ(i * 16 + fm, (k0 + fq) * 2));
#pragma unroll
        for (int j = 0; j < 4; ++j)
            bfr[j] = *(const bf16x8*)(Bs + (wave * 64 + j * 16 + fm) * 32 + fq);
#pragma unroll
        for (int i = 0; i < 2; ++i)
#pragma unroll
            for (int j = 0; j < 4; ++j)
                acc[i][j] = __builtin_amdgcn_mfma_f32_16x16x32_bf16(af[i], bfr[j], acc[i][j], 0, 0, 0);
        if (k0 + 32 < K) {
            // ds_reads of this chunk complete before overwriting their LDS rows
            asm volatile("s_waitcnt lgkmcnt(0)" ::: "memory");
            __builtin_amdgcn_sched_barrier(0);
            stage_B(Bs, Wt, K, k0 + 32, wave, lane);
        }
    }
    __syncthreads();   // all waves done reading buf
}

// ---- epilogue: acc -> buf (bf16, swizzled) + column stats atomics ----
__device__ __forceinline__ void stage_epilogue(f32x4 (&acc)[2][4], short* buf,
                                               float* redS, float* redQ,
                                               float* __restrict__ statsOut,
                                               int wave, int lane, int tid, int bcp) {
    const int fm = lane & 15;
    const int row4 = (lane >> 4) * 4;
    const int ocol = wave * 64 + fm;
#pragma unroll
    for (int i = 0; i < 2; ++i)
#pragma unroll
        for (int j = 0; j < 4; ++j)
#pragma unroll
            for (int r = 0; r < 4; ++r)
                *(short*)((char*)buf + SWZ(row4 + i * 16 + r, (ocol + j * 16) * 2)) =
                    (short)f2b(acc[i][j][r]);

#pragma unroll
    for (int j = 0; j < 4; ++j) {
        float s = 0.f, q = 0.f;
#pragma unroll
        for (int i = 0; i < 2; ++i)
#pragma unroll
            for (int r = 0; r < 4; ++r) {
                float v = acc[i][j][r];
                s += v; q += v * v;
            }
        s += __shfl_xor(s, 16, 64); s += __shfl_xor(s, 32, 64);
        q += __shfl_xor(q, 16, 64); q += __shfl_xor(q, 32, 64);
        if (lane < 16) {
            redS[wave * 64 + j * 16 + lane] = s;
            redQ[wave * 64 + j * 16 + lane] = q;
        }
    }
    __syncthreads();
    atomicAdd(&statsOut[bcp + tid], redS[tid]);
    atomicAdd(&statsOut[bcp + 256 + tid], redQ[tid]);
}

// ---- BN affine tables ----
__device__ __forceinline__ void build_tbl_glu(const float* __restrict__ st,
                                              const float* __restrict__ pg,
                                              const float* __restrict__ pb,
                                              int colOff, int K, int tid, float* tbl) {
    if (tid < K) {
        const int ch = colOff + tid;
        const int cg = ch + 128;
        float sA = 0.f, qA = 0.f, sG = 0.f, qG = 0.f;
#pragma unroll
        for (int cp = 0; cp < NCPY; ++cp) {
            const float* p = st + cp * 512;
            sA += p[ch]; qA += p[256 + ch];
            sG += p[cg]; qG += p[256 + cg];
        }
        float ma = sA * INV_B, va = qA * INV_B - ma * ma;
        float scA = pg[ch] * rsqrtf(va + BN_EPS);
        tbl[tid] = scA; tbl[K + tid] = pb[ch] - ma * scA;
        float mg = sG * INV_B, vg = qG * INV_B - mg * mg;
        float scG = pg[cg] * rsqrtf(vg + BN_EPS);
        tbl[2 * K + tid] = scG; tbl[3 * K + tid] = pb[cg] - mg * scG;
    }
    __syncthreads();
}

__device__ __forceinline__ void build_tbl_mask(const float* __restrict__ st,
                                               const float* __restrict__ gcp,
                                               const float* __restrict__ bcp_,
                                               int tid, float* tbl) {
    float s = 0.f, q = 0.f;
#pragma unroll
    for (int cp = 0; cp < NCPY; ++cp) {
        s += st[cp * 512 + tid];
        q += st[cp * 512 + 256 + tid];
    }
    float mean = s * INV_B, var = q * INV_B - mean * mean;
    float scl = gcp[tid] * rsqrtf(var + BN_EPS);
    tbl[tid] = scl;
    tbl[256 + tid] = bcp_[tid] - mean * scl;
    __syncthreads();
}

// ---- GLU prologue: P-pairs in buf -> BN+GLU(+res) -> A into buf (in place) ----
template <int K, bool RES, bool WH, int RB>
__device__ __forceinline__ void glu_prologue(short* buf, const float* tbl,
                                             int tid, int colOff, bf16x4* h) {
    const int ar = tid >> 3;
    const int ac = (tid & 7) * 4;
#pragma unroll
    for (int c = 0; c < K / 32; ++c) {
        const int kk = c * 32 + ac;
        bf16x4 lo = *(const bf16x4*)((const char*)buf + SWZ(ar, (colOff + kk) * 2));
        bf16x4 hi = *(const bf16x4*)((const char*)buf + SWZ(ar, (colOff + kk + 128) * 2));
        float4 a0 = *(const float4*)&tbl[kk];
        float4 h0 = *(const float4*)&tbl[K + kk];
        float4 g0 = *(const float4*)&tbl[2 * K + kk];
        float4 s0 = *(const float4*)&tbl[3 * K + kk];
        const float scA[4] = {a0.x, a0.y, a0.z, a0.w};
        const float shA[4] = {h0.x, h0.y, h0.z, h0.w};
        const float scG[4] = {g0.x, g0.y, g0.z, g0.w};
        const float shG[4] = {s0.x, s0.y, s0.z, s0.w};
        bf16x4 o4;
#pragma unroll
        for (int e = 0; e < 4; ++e) {
            float na = b2f((unsigned short)lo[e]) * scA[e] + shA[e];
            float ng = b2f((unsigned short)hi[e]) * scG[e] + shG[e];
            float v = na * (1.0f / (1.0f + __expf(-ng)));
            if (RES) v = (v + b2f((unsigned short)h[RB + c][e])) * SQRT_HALF;
            o4[e] = (short)f2b(v);
        }
        *(bf16x4*)((char*)buf + SWZ(ar, kk * 2)) = o4;
        if (WH) h[c] = o4;
    }
}

// ---- mask phase (mega): coef P in buf -> BN -> softmax -> cmpl'/masked/entropy ----
template <int MODE>   // 0 first, 1 middle, 2 entropy-only
__device__ __forceinline__ void mask_phase(short* buf, const float* tbl,
                                           const unsigned short* __restrict__ xb,
                                           unsigned short* cmpl, float* ent, float* went,
                                           int tid, int wave, int lane, int row0, int bid) {
    const int r = tid >> 3;
    const int cq = tid & 7;
    const size_t grow = (size_t)(row0 + r) * 256;

    float l[32];
    float mx = -1e30f;
#pragma unroll
    for (int e = 0; e < 4; ++e) {
        const int c = cq * 32 + e * 8;
        bf16x8 pv = *(const bf16x8*)((const char*)buf + SWZ(r, c * 2));
        bf16x8 cv;
        if (MODE != 0) cv = *(const bf16x8*)(cmpl + grow + c);
        float4 s0 = *(const float4*)&tbl[c], s1 = *(const float4*)&tbl[c + 4];
        float4 h0 = *(const float4*)&tbl[256 + c], h1 = *(const float4*)&tbl[256 + c + 4];
        const float* sp0 = (const float*)&s0; const float* sp1 = (const float*)&s1;
        const float* hp0 = (const float*)&h0; const float* hp1 = (const float*)&h1;
#pragma unroll
        for (int t = 0; t < 8; ++t) {
            float scl = (t < 4) ? sp0[t] : sp1[t - 4];
            float shf = (t < 4) ? hp0[t] : hp1[t - 4];
            float cl = (MODE != 0) ? b2f((unsigned short)cv[t]) : 1.0f;
            float v = (b2f((unsigned short)pv[t]) * scl + shf) * cl;
            l[e * 8 + t] = v;
            mx = fmaxf(mx, v);
        }
    }
    mx = fmaxf(mx, __shfl_xor(mx, 1, 64));
    mx = fmaxf(mx, __shfl_xor(mx, 2, 64));
    mx = fmaxf(mx, __shfl_xor(mx, 4, 64));

    float ssum = 0.f;
#pragma unroll
    for (int i = 0; i < 32; ++i) { l[i] = __expf(l[i] - mx); ssum += l[i]; }
    ssum += __shfl_xor(ssum, 1, 64);
    ssum += __shfl_xor(ssum, 2, 64);
    ssum += __shfl_xor(ssum, 4, 64);
    const float inv = 1.0f / ssum;

    float et = 0.f;
#pragma unroll
    for (int e = 0; e < 4; ++e) {
        const int c = cq * 32 + e * 8;
        bf16x8 xv, cv2;
        if (MODE != 2) xv = *(const bf16x8*)(xb + grow + c);
        if (MODE == 1) cv2 = *(const bf16x8*)(cmpl + grow + c);
        bf16x8 mo, co;
#pragma unroll
        for (int t = 0; t < 8; ++t) {
            float m = l[e * 8 + t] * inv;
            et -= m * __logf(m + SM_EPS);
            if (MODE != 2) {
                float cl = (MODE == 1) ? b2f((unsigned short)cv2[t]) : 1.0f;
                co[t] = (short)f2b(cl * (1.5f - m));
                mo[t] = (short)f2b(m * b2f((unsigned short)xv[t]));
            }
        }
        if (MODE != 2) {
            *(bf16x8*)(cmpl + grow + c) = co;
            *(bf16x8*)((char*)buf + SWZ(r, c * 2)) = mo;
        }
    }
    et += __shfl_xor(et, 1, 64);
    et += __shfl_xor(et, 2, 64);
    et += __shfl_xor(et, 4, 64);
    float wet = waveSumAll(et) * 0.125f;
    if (lane == 0) went[wave] = wet;
    __syncthreads();
    if (tid == 0) {
        float v = went[0] + went[1] + went[2] + went[3];
        atomicAdd(&ent[(bid & 255) << 5], v * (INV_B * 0.2f));
    }
}

// =========================== MEGA (persistent, leader-release barrier) ===========================
__global__ __launch_bounds__(256, 4) void mega(
    const float* __restrict__ x,
    const float* __restrict__ enc_g, const float* __restrict__ enc_b,
    const float* __restrict__ g1, const float* __restrict__ b1,
    const float* __restrict__ g2, const float* __restrict__ b2,
    const float* __restrict__ g3, const float* __restrict__ b3,
    const float* __restrict__ g4, const float* __restrict__ b4,
    const float* __restrict__ gc, const float* __restrict__ bc,
    const float* __restrict__ W1f, const float* __restrict__ W2f,
    const float* __restrict__ W3f, const float* __restrict__ W4f,
    const float* __restrict__ Wcf,
    unsigned short* __restrict__ W1t, unsigned short* __restrict__ W2t,
    unsigned short* __restrict__ W3t, unsigned short* __restrict__ W4t,
    unsigned short* __restrict__ Wct,
    unsigned short* __restrict__ xb, unsigned short* __restrict__ cmpl,
    float* __restrict__ stats, float* __restrict__ ent,
    unsigned int* __restrict__ bar,
    float* __restrict__ out)
{
    __shared__ short buf[32 * 256];   // 16 KB A/P tile (swizzled)
    __shared__ short Bs[256 * 32];    // 16 KB weight staging (wave-private rows)
    __shared__ float redS[256], redQ[256];
    __shared__ float tbl[512];
    __shared__ float went[4];

    const int tid  = threadIdx.x;
    const int wave = tid >> 6;
    const int lane = tid & 63;
    const int bid  = blockIdx.x;
    const int row0 = bid * 32;
    const int bcp  = (bid & (NCPY - 1)) * 512;

    unsigned int* rel = bar + 64 * 32;   // release word, own line
    unsigned int bgen = 0;
#define GSYNC() do { ++bgen; grid_sync_lr(bar, rel, bgen, bid, tid); } while (0)

    // ---------- pre-sync: weight prep (blocks 0..135) + x col-stats (all) ----------
    if (bid < 136) {
        const int m = bid >> 3, kz = bid & 7, n = tid;
        const float* src; unsigned short* dst; int K;
        if (m == 0)      { src = W1f;                        dst = W1t;               K = 256; }
        else if (m == 1) { src = W2f;                        dst = W2t;               K = 128; }
        else if (m < 7)  { int i = m - 2;  src = W3f + (size_t)i * 128 * 256; dst = W3t + (size_t)i * 32768; K = 128; }
        else if (m < 12) { int i = m - 7;  src = W4f + (size_t)i * 128 * 256; dst = W4t + (size_t)i * 32768; K = 128; }
        else             { int i = m - 12; src = Wcf + (size_t)i * 64 * 256;  dst = Wct + (size_t)i * 16384; K = 64; }
        const int k0 = kz * 32;
        if (k0 < K)
            for (int k = k0; k < k0 + 32; ++k)
                dst[(size_t)n * K + k] = f2b(src[(size_t)k * 256 + n]);
    }
    {   // col stats of x for this block's 32 rows (buf reused as f32 scratch)
        float* red = (float*)buf;
        const int sub = wave;
        const int c4  = lane << 2;
        float s[4] = {0.f, 0.f, 0.f, 0.f}, q[4] = {0.f, 0.f, 0.f, 0.f};
#pragma unroll 8
        for (int i = 0; i < 8; ++i) {
            const int row = row0 + i * 4 + sub;
            float4 v = *(const float4*)(x + (size_t)row * 256 + c4);
            s[0] += v.x; q[0] += v.x * v.x;
            s[1] += v.y; q[1] += v.y * v.y;
            s[2] += v.z; q[2] += v.z * v.z;
            s[3] += v.w; q[3] += v.w * v.w;
        }
#pragma unroll
        for (int e = 0; e < 4; ++e) {
            red[sub * 512 + c4 + e] = s[e];
            red[sub * 512 + 256 + c4 + e] = q[e];
        }
        __syncthreads();
        float sS = red[tid] + red[512 + tid] + red[1024 + tid] + red[1536 + tid];
        float sQ = red[256 + tid] + red[768 + tid] + red[1280 + tid] + red[1792 + tid];
        atomicAdd(&stats[bcp + tid], sS);
        atomicAdd(&stats[bcp + 256 + tid], sQ);
    }
    GSYNC();

    // ---------- stage 0b: normalize x -> buf + xb + out ----------
    stage_B(Bs, W1t, 256, 0, wave, lane);   // chunk-0 of W1 for ni=0 stage-1
    {
        float s = 0.f, q = 0.f;
#pragma unroll
        for (int cp = 0; cp < NCPY; ++cp) {
            s += stats[cp * 512 + tid];
            q += stats[cp * 512 + 256 + tid];
        }
        float mean = s * INV_B, var = q * INV_B - mean * mean;
        float scl = enc_g[tid] * rsqrtf(var + BN_EPS);
        tbl[tid] = scl;
        tbl[256 + tid] = enc_b[tid] - mean * scl;
    }
    __syncthreads();
    {
        const int r = tid >> 3, cq = tid & 7;
        const size_t grow = (size_t)(row0 + r) * 256;
#pragma unroll
        for (int e = 0; e < 4; ++e) {
            const int c = cq * 32 + e * 8;
            float4 xa = *(const float4*)(x + grow + c);
            float4 xc = *(const float4*)(x + grow + c + 4);
            const float xv[8] = {xa.x, xa.y, xa.z, xa.w, xc.x, xc.y, xc.z, xc.w};
            float4 s0 = *(const float4*)&tbl[c], s1 = *(const float4*)&tbl[c + 4];
            float4 f0 = *(const float4*)&tbl[256 + c], f1 = *(const float4*)&tbl[256 + c + 4];
            const float sc[8] = {s0.x, s0.y, s0.z, s0.w, s1.x, s1.y, s1.z, s1.w};
            const float sh[8] = {f0.x, f0.y, f0.z, f0.w, f1.x, f1.y, f1.z, f1.w};
            float n[8];
            bf16x8 o8;
#pragma unroll
            for (int t = 0; t < 8; ++t) {
                n[t] = xv[t] * sc[t] + sh[t];
                o8[t] = (short)f2b(n[t]);
            }
            *(bf16x8*)((char*)buf + SWZ(r, c * 2)) = o8;
            *(bf16x8*)(xb + grow + c) = o8;
            if (c < OUTD) {
                float4 o1 = make_float4(5.f * fmaxf(n[0], 0.f), 5.f * fmaxf(n[1], 0.f),
                                        5.f * fmaxf(n[2], 0.f), 5.f * fmaxf(n[3], 0.f));
                float4 o2 = make_float4(5.f * fmaxf(n[4], 0.f), 5.f * fmaxf(n[5], 0.f),
                                        5.f * fmaxf(n[6], 0.f), 5.f * fmaxf(n[7], 0.f));
                *(float4*)(out + (size_t)(row0 + r) * OUTD + c) = o1;
                *(float4*)(out + (size_t)(row0 + r) * OUTD + c + 4) = o2;
            }
        }
    }

    // ---------- 5 iterations x 5 stages ----------
    // Next-stage chunk-0 weight DMA is issued BEFORE each GSYNC: the barrier's
    // entry __syncthreads drains it, so post-barrier GEMMs start with Bs hot.
    f32x4 acc[2][4];
    bf16x4 h[4];

    for (int ni = 0; ni < 5; ++ni) {
        float* s1 = stats + (size_t)(1 + ni * 5 + 0) * SLOT;
        float* s2 = stats + (size_t)(1 + ni * 5 + 1) * SLOT;
        float* s3 = stats + (size_t)(1 + ni * 5 + 2) * SLOT;
        float* s4 = stats + (size_t)(1 + ni * 5 + 3) * SLOT;
        float* s5 = stats + (size_t)(1 + ni * 5 + 4) * SLOT;

        // -- stage 1: (mask for ni>0) + GEMM vs W1t (K=256); W1t c0 pre-staged --
        if (ni > 0) {
            float* s5p = stats + (size_t)(1 + (ni - 1) * 5 + 4) * SLOT;
            build_tbl_mask(s5p, gc + (ni - 1) * 256, bc + (ni - 1) * 256, tid, tbl);
            if (ni == 1)
                mask_phase<0>(buf, tbl, xb, cmpl, ent, went, tid, wave, lane, row0, bid);
            else
                mask_phase<1>(buf, tbl, xb, cmpl, ent, went, tid, wave, lane, row0, bid);
        }
        gemm_core(buf, Bs, W1t, 256, wave, lane, acc);
        stage_epilogue(acc, buf, redS, redQ, s1, wave, lane, tid, bcp);
        stage_B(Bs, W2t, 128, 0, wave, lane);
        GSYNC();

        // -- stage 2: GLU(P1) -> GEMM vs W2t --
        build_tbl_glu(s1, g1, b1, 0, 128, tid, tbl);
        glu_prologue<128, false, true, 0>(buf, tbl, tid, 0, h);
        gemm_core(buf, Bs, W2t, 128, wave, lane, acc);
        stage_epilogue(acc, buf, redS, redQ, s2, wave, lane, tid, bcp);
        stage_B(Bs, W3t + (size_t)ni * 32768, 128, 0, wave, lane);
        GSYNC();

        // -- stage 3: GLU(P2)+res h1 -> GEMM vs W3t[ni] --
        build_tbl_glu(s2, g2, b2, 0, 128, tid, tbl);
        glu_prologue<128, true, true, 0>(buf, tbl, tid, 0, h);
        gemm_core(buf, Bs, W3t + (size_t)ni * 32768, 128, wave, lane, acc);
        stage_epilogue(acc, buf, redS, redQ, s3, wave, lane, tid, bcp);
        stage_B(Bs, W4t + (size_t)ni * 32768, 128, 0, wave, lane);
        GSYNC();

        // -- stage 4: GLU(P3)+res h2 -> GEMM vs W4t[ni] --
        build_tbl_glu(s3, g3 + ni * 256, b3 + ni * 256, 0, 128, tid, tbl);
        glu_prologue<128, true, true, 0>(buf, tbl, tid, 0, h);
        gemm_core(buf, Bs, W4t + (size_t)ni * 32768, 128, wave, lane, acc);
        stage_epilogue(acc, buf, redS, redQ, s4, wave, lane, tid, bcp);
        stage_B(Bs, Wct + (size_t)ni * 16384, 64, 0, wave, lane);
        GSYNC();

        // -- stage 5: fc = GLU(P4)[:,64:]+res h3[:,64:] -> GEMM vs Wct[ni] (K=64) --
        build_tbl_glu(s4, g4 + ni * 256, b4 + ni * 256, 64, 64, tid, tbl);
        glu_prologue<64, true, false, 2>(buf, tbl, tid, 64, h);
        gemm_core(buf, Bs, Wct + (size_t)ni * 16384, 64, wave, lane, acc);
        stage_epilogue(acc, buf, redS, redQ, s5, wave, lane, tid, bcp);
        if (ni < 4) stage_B(Bs, W1t, 256, 0, wave, lane);
        GSYNC();
    }

    // ---------- final: entropy of the last coef ----------
    build_tbl_mask(stats + (size_t)(1 + 4 * 5 + 4) * SLOT,
                   gc + 4 * 256, bc + 4 * 256, tid, tbl);
    mask_phase<2>(buf, tbl, xb, cmpl, ent, went, tid, wave, lane, row0, bid);
    GSYNC();

    if (bid == 0 && wave == 0) {
        float v = 0.f;
#pragma unroll
        for (int i = 0; i < 4; ++i) v += ent[(lane + 64 * i) << 5];
        v = waveSumAll(v);
        if (lane == 0) out[(size_t)BSZ * OUTD] = v;
    }
#undef GSYNC
}

// ======================= FALLBACK PATH (proven R2 pipeline) =======================
__global__ __launch_bounds__(256) void prep_w(
    const float* __restrict__ W1, const float* __restrict__ W2,
    const float* __restrict__ W3, const float* __restrict__ W4,
    const float* __restrict__ Wc,
    unsigned short* __restrict__ W1t, unsigned short* __restrict__ W2t,
    unsigned short* __restrict__ W3t, unsigned short* __restrict__ W4t,
    unsigned short* __restrict__ Wct)
{
    const int m = blockIdx.x, kz = blockIdx.y, n = threadIdx.x;
    const float* src; unsigned short* dst; int K;
    if (m == 0)      { src = W1;                        dst = W1t;               K = 256; }
    else if (m == 1) { src = W2;                        dst = W2t;               K = 128; }
    else if (m < 7)  { int i = m - 2;  src = W3 + (size_t)i * 128 * 256; dst = W3t + (size_t)i * 32768; K = 128; }
    else if (m < 12) { int i = m - 7;  src = W4 + (size_t)i * 128 * 256; dst = W4t + (size_t)i * 32768; K = 128; }
    else             { int i = m - 12; src = Wc + (size_t)i * 64 * 256;  dst = Wct + (size_t)i * 16384; K = 64; }
    const int k0 = kz * 32;
    if (k0 >= K) return;
    for (int k = k0; k < k0 + 32; ++k)
        dst[(size_t)n * K + k] = f2b(src[(size_t)k * 256 + n]);
}

__global__ __launch_bounds__(256) void colstats(const float* __restrict__ X,
                                                float* __restrict__ st0) {
    __shared__ float red[4][512];
    const int sub = threadIdx.x >> 6;
    const int c4  = (threadIdx.x & 63) << 2;
    float s[4] = {0.f, 0.f, 0.f, 0.f}, q[4] = {0.f, 0.f, 0.f, 0.f};
#pragma unroll 8
    for (int i = 0; i < 8; ++i) {
        const int row = blockIdx.x * 32 + i * 4 + sub;
        float4 v = *(const float4*)(X + (size_t)row * 256 + c4);
        s[0] += v.x; q[0] += v.x * v.x;
        s[1] += v.y; q[1] += v.y * v.y;
        s[2] += v.z; q[2] += v.z * v.z;
        s[3] += v.w; q[3] += v.w * v.w;
    }
#pragma unroll
    for (int e = 0; e < 4; ++e) {
        red[sub][c4 + e] = s[e];
        red[sub][256 + c4 + e] = q[e];
    }
    __syncthreads();
    const int t = threadIdx.x;
    const int cp = (blockIdx.x & (NCPY - 1)) * 512;
    float sS = red[0][t] + red[1][t] + red[2][t] + red[3][t];
    float sQ = red[0][256 + t] + red[1][256 + t] + red[2][256 + t] + red[3][256 + t];
    atomicAdd(&st0[cp + t], sS);
    atomicAdd(&st0[cp + 256 + t], sQ);
}

__global__ __launch_bounds__(256) void norm_x(const float* __restrict__ x,
                                              const float* __restrict__ st0,
                                              const float* __restrict__ g,
                                              const float* __restrict__ b,
                                              unsigned short* __restrict__ xb,
                                              float* __restrict__ out) {
    const int i4 = blockIdx.x * 256 + threadIdx.x;
    const int row = i4 >> 6, c4 = (i4 & 63) << 2;
    float4 xv = *(const float4*)(x + (size_t)row * 256 + c4);
    float sS[4] = {0.f, 0.f, 0.f, 0.f}, sQ[4] = {0.f, 0.f, 0.f, 0.f};
#pragma unroll
    for (int cp = 0; cp < NCPY; ++cp) {
        float4 a = *(const float4*)&st0[cp * 512 + c4];
        float4 q = *(const float4*)&st0[cp * 512 + 256 + c4];
        sS[0] += a.x; sS[1] += a.y; sS[2] += a.z; sS[3] += a.w;
        sQ[0] += q.x; sQ[1] += q.y; sQ[2] += q.z; sQ[3] += q.w;
    }
    float4 gv = *(const float4*)&g[c4];
    float4 bv = *(const float4*)&b[c4];
    const float* xp = (const float*)&xv;
    const float* gp = (const float*)&gv; const float* bp = (const float*)&bv;
    float n[4];
    ushort4 ob;
    unsigned short* obp = (unsigned short*)&ob;
#pragma unroll
    for (int e = 0; e < 4; ++e) {
        float mean = sS[e] * INV_B;
        float var  = sQ[e] * INV_B - mean * mean;
        float sc   = gp[e] * rsqrtf(var + BN_EPS);
        float sh   = bp[e] - mean * sc;
        n[e] = xp[e] * sc + sh;
        obp[e] = f2b(n[e]);
    }
    *(ushort4*)(xb + (size_t)row * 256 + c4) = ob;
    if (c4 < OUTD) {
        float4 ov = make_float4(5.0f * fmaxf(n[0], 0.f), 5.0f * fmaxf(n[1], 0.f),
                                5.0f * fmaxf(n[2], 0.f), 5.0f * fmaxf(n[3], 0.f));
        *(float4*)(out + (size_t)row * OUTD + c4) = ov;
    }
}

__device__ __forceinline__ void gemm_epilogue(
    f32x4 (&acc)[2][4], int row0, int wave, int lane, int tid, int bcp,
    float* redS, float* redQ,
    unsigned short* __restrict__ Pout, float* __restrict__ statsOut)
{
    const int fm = lane & 15;
    const int orow = row0 + (lane >> 4) * 4;
    const int ocol = wave * 64 + fm;
#pragma unroll
    for (int i = 0; i < 2; ++i)
#pragma unroll
        for (int j = 0; j < 4; ++j)
#pragma unroll
            for (int r = 0; r < 4; ++r)
                Pout[(size_t)(orow + i * 16 + r) * 256 + (ocol + j * 16)] = f2b(acc[i][j][r]);

#pragma unroll
    for (int j = 0; j < 4; ++j) {
        float s = 0.f, q = 0.f;
#pragma unroll
        for (int i = 0; i < 2; ++i)
#pragma unroll
            for (int r = 0; r < 4; ++r) {
                float v = acc[i][j][r];
                s += v; q += v * v;
            }
        s += __shfl_xor(s, 16, 64); s += __shfl_xor(s, 32, 64);
        q += __shfl_xor(q, 16, 64); q += __shfl_xor(q, 32, 64);
        if (lane < 16) {
            redS[wave * 64 + j * 16 + lane] = s;
            redQ[wave * 64 + j * 16 + lane] = q;
        }
    }
    __syncthreads();
    atomicAdd(&statsOut[bcp + tid], redS[tid]);
    atomicAdd(&statsOut[bcp + 256 + tid], redQ[tid]);
}

__global__ __launch_bounds__(256) void gemm_bf16(
    const unsigned short* __restrict__ A,
    const unsigned short* __restrict__ Wt, int K,
    unsigned short* __restrict__ P,
    float* __restrict__ statsOut)
{
    __shared__ short As[32 * 32];
    __shared__ short Bs[256 * 32];
    __shared__ float redS[256], redQ[256];

    const int tid  = threadIdx.x;
    const int wave = tid >> 6;
    const int lane = tid & 63;
    const int row0 = blockIdx.x * 32;
    const int bcp  = (blockIdx.x & (NCPY - 1)) * 512;

    const int sr = lane >> 2;
    const int sc = (lane & 3) * 8;
    const int fm = lane & 15;
    const int fq = (lane >> 4) * 8;

    f32x4 acc[2][4];
#pragma unroll
    for (int i = 0; i < 2; ++i)
#pragma unroll
        for (int j = 0; j < 4; ++j)
            acc[i][j] = (f32x4){0.f, 0.f, 0.f, 0.f};

    for (int k0 = 0; k0 < K; k0 += 32) {
        if (wave < 2)
            async16(A + (size_t)(row0 + wave * 16 + sr) * K + k0 + sc,
                    (void*)(As + wave * 512 + lane * 8));
#pragma unroll
        for (int t = 0; t < 4; ++t) {
            const int wr = wave * 64 + t * 16 + sr;
            async16(Wt + (size_t)wr * K + k0 + sc,
                    (void*)(Bs + (wave * 4 + t) * 512 + lane * 8));
        }
        __syncthreads();

        bf16x8 af[2], bfr[4];
#pragma unroll
        for (int i = 0; i < 2; ++i)
            af[i] = *(const bf16x8*)(As + (i * 16 + fm) * 32 + fq);
#pragma unroll
        for (int j = 0; j < 4; ++j)
            bfr[j] = *(const bf16x8*)(Bs + (wave * 64 + j * 16 + fm) * 32 + fq);
#pragma unroll
        for (int i = 0; i < 2; ++i)
#pragma unroll
            for (int j = 0; j < 4; ++j)
                acc[i][j] = __builtin_amdgcn_mfma_f32_16x16x32_bf16(af[i], bfr[j], acc[i][j], 0, 0, 0);
        __syncthreads();
    }

    gemm_epilogue(acc, row0, wave, lane, tid, bcp, redS, redQ, P, statsOut);
}

template <int MODE>
__global__ __launch_bounds__(256) void gemm_mask(
    const unsigned short* Pc,
    const float* __restrict__ cstats,
    const float* __restrict__ gc, const float* __restrict__ bc,
    const unsigned short* __restrict__ xb,
    unsigned short* __restrict__ cmpl,
    float* __restrict__ ent,
    const unsigned short* __restrict__ Wt,
    unsigned short* Pout,
    float* __restrict__ statsOut)
{
    __shared__ short Am[32 * 256];
    __shared__ short Bs[256 * 32];
    __shared__ float redS[256], redQ[256];
    __shared__ float tScl[256], tShf[256];
    __shared__ float went[4];

    const int tid  = threadIdx.x;
    const int wave = tid >> 6;
    const int lane = tid & 63;
    const int row0 = blockIdx.x * 32;
    const int bcp  = (blockIdx.x & (NCPY - 1)) * 512;

    const int sr = lane >> 2;
    const int sc = (lane & 3) * 8;

#pragma unroll
    for (int t = 0; t < 4; ++t) {
        const int wr = wave * 64 + t * 16 + sr;
        async16(Wt + (size_t)wr * 256 + sc,
                (void*)(Bs + (wave * 4 + t) * 512 + lane * 8));
    }

    {
        float s = 0.f, q = 0.f;
#pragma unroll
        for (int cp = 0; cp < NCPY; ++cp) {
            s += cstats[cp * 512 + tid];
            q += cstats[cp * 512 + 256 + tid];
        }
        float mean = s * INV_B, var = q * INV_B - mean * mean;
        float scl_ = gc[tid] * rsqrtf(var + BN_EPS);
        tScl[tid] = scl_;
        tShf[tid] = bc[tid] - mean * scl_;
    }
    __syncthreads();

    const int r  = tid >> 3;
    const int cq = tid & 7;
    const size_t grow = (size_t)(row0 + r) * 256;

    float l[32];
    float mx = -1e30f;
#pragma unroll
    for (int e = 0; e < 4; ++e) {
        const int c = cq * 32 + e * 8;
        bf16x8 pv = *(const bf16x8*)(Pc + grow + c);
        bf16x8 cv;
        if (MODE) cv = *(const bf16x8*)(cmpl + grow + c);
        float4 s0 = *(const float4*)&tScl[c], s1 = *(const float4*)&tScl[c + 4];
        float4 h0 = *(const float4*)&tShf[c], h1 = *(const float4*)&tShf[c + 4];
        const float* sp0 = (const float*)&s0; const float* sp1 = (const float*)&s1;
        const float* hp0 = (const float*)&h0; const float* hp1 = (const float*)&h1;
#pragma unroll
        for (int t = 0; t < 8; ++t) {
            float scl_ = (t < 4) ? sp0[t] : sp1[t - 4];
            float shf_ = (t < 4) ? hp0[t] : hp1[t - 4];
            float cl = MODE ? b2f((unsigned short)cv[t]) : 1.0f;
            float v = (b2f((unsigned short)pv[t]) * scl_ + shf_) * cl;
            l[e * 8 + t] = v;
            mx = fmaxf(mx, v);
        }
    }
    mx = fmaxf(mx, __shfl_xor(mx, 1, 64));
    mx = fmaxf(mx, __shfl_xor(mx, 2, 64));
    mx = fmaxf(mx, __shfl_xor(mx, 4, 64));

    float ssum = 0.f;
#pragma unroll
    for (int i = 0; i < 32; ++i) { l[i] = __expf(l[i] - mx); ssum += l[i]; }
    ssum += __shfl_xor(ssum, 1, 64);
    ssum += __shfl_xor(ssum, 2, 64);
    ssum += __shfl_xor(ssum, 4, 64);
    const float inv = 1.0f / ssum;

    float et = 0.f;
#pragma unroll
    for (int e = 0; e < 4; ++e) {
        const int c = cq * 32 + e * 8;
        bf16x8 xv = *(const bf16x8*)(xb + grow + c);
        bf16x8 cv2;
        if (MODE) cv2 = *(const bf16x8*)(cmpl + grow + c);
        bf16x8 mo, co;
#pragma unroll
        for (int t = 0; t < 8; ++t) {
            float m = l[e * 8 + t] * inv;
            et -= m * __logf(m + SM_EPS);
            float cl = MODE ? b2f((unsigned short)cv2[t]) : 1.0f;
            co[t] = (short)f2b(cl * (1.5f - m));
            mo[t] = (short)f2b(m * b2f((unsigned short)xv[t]));
        }
        *(bf16x8*)(cmpl + grow + c) = co;
        unsigned int byte = (unsigned int)(r * 512 + c * 2);
        byte ^= ((unsigned int)(r & 7)) << 4;
        *(bf16x8*)((char*)Am + byte) = mo;
    }
    et += __shfl_xor(et, 1, 64);
    et += __shfl_xor(et, 2, 64);
    et += __shfl_xor(et, 4, 64);
    float wet = waveSumAll(et) * 0.125f;
    if (lane == 0) went[wave] = wet;
    __syncthreads();
    if (tid == 0) {
        float v = went[0] + went[1] + went[2] + went[3];
        atomicAdd(&ent[(blockIdx.x & 255) << 5], v * (INV_B * 0.2f));
    }

    const int fm = lane & 15;
    const int fq = (lane >> 4) * 8;

    f32x4 acc[2][4];
#pragma unroll
    for (int i = 0; i < 2; ++i)
#pragma unroll
        for (int j = 0; j < 4; ++j)
            acc[i][j] = (f32x4){0.f, 0.f, 0.f, 0.f};

    for (int k0 = 0; k0 < 256; k0 += 32) {
        bf16x8 af[2], bfr[4];
#pragma unroll
        for (int i = 0; i < 2; ++i) {
            const int row = i * 16 + fm;
            unsigned int byte = (unsigned int)(row * 512 + (k0 + fq) * 2);
            byte ^= ((unsigned int)(row & 7)) << 4;
            af[i] = *(const bf16x8*)((const char*)Am + byte);
        }
#pragma unroll
        for (int j = 0; j < 4; ++j)
            bfr[j] = *(const bf16x8*)(Bs + (wave * 64 + j * 16 + fm) * 32 + fq);
#pragma unroll
        for (int i = 0; i < 2; ++i)
#pragma unroll
            for (int j = 0; j < 4; ++j)
                acc[i][j] = __builtin_amdgcn_mfma_f32_16x16x32_bf16(af[i], bfr[j], acc[i][j], 0, 0, 0);
        __syncthreads();
        if (k0 + 32 < 256) {
#pragma unroll
            for (int t = 0; t < 4; ++t) {
                const int wr = wave * 64 + t * 16 + sr;
                async16(Wt + (size_t)wr * 256 + (k0 + 32) + sc,
                        (void*)(Bs + (wave * 4 + t) * 512 + lane * 8));
            }
            __syncthreads();
        }
    }

    gemm_epilogue(acc, row0, wave, lane, tid, bcp, redS, redQ, Pout, statsOut);
}

template <bool RES, bool WRITE_H>
__global__ __launch_bounds__(256) void gemm_glu(
    const unsigned short* __restrict__ Pprev,
    const float* __restrict__ pstats,
    const float* __restrict__ pg,
    const float* __restrict__ pb,
    const unsigned short* __restrict__ res,
    int colOff,
    const unsigned short* __restrict__ Wt, int K,
    unsigned short* __restrict__ Pout,
    float* __restrict__ statsOut,
    unsigned short* __restrict__ hOut)
{
    __shared__ short As[32 * 32];
    __shared__ short Bs[256 * 32];
    __shared__ float redS[256], redQ[256];
    __shared__ float tScA[128], tShA[128], tScG[128], tShG[128];

    const int tid  = threadIdx.x;
    const int wave = tid >> 6;
    const int lane = tid & 63;
    const int row0 = blockIdx.x * 32;
    const int bcp  = (blockIdx.x & (NCPY - 1)) * 512;

    if (tid < K) {
        const int ch = colOff + tid;
        const int cg = ch + 128;
        float sA = 0.f, qA = 0.f, sG = 0.f, qG = 0.f;
#pragma unroll
        for (int cp = 0; cp < NCPY; ++cp) {
            const float* p = pstats + cp * 512;
            sA += p[ch]; qA += p[256 + ch];
            sG += p[cg]; qG += p[256 + cg];
        }
        float ma = sA * INV_B, va = qA * INV_B - ma * ma;
        float scA = pg[ch] * rsqrtf(va + BN_EPS);
        tScA[tid] = scA; tShA[tid] = pb[ch] - ma * scA;
        float mg = sG * INV_B, vg = qG * INV_B - mg * mg;
        float scG = pg[cg] * rsqrtf(vg + BN_EPS);
        tScG[tid] = scG; tShG[tid] = pb[cg] - mg * scG;
    }
    __syncthreads();

    const int sr = lane >> 2;
    const int sc = (lane & 3) * 8;
    const int ar = tid >> 3;
    const int ac = (tid & 7) * 4;
    const int fm = lane & 15;
    const int fq = (lane >> 4) * 8;

    f32x4 acc[2][4];
#pragma unroll
    for (int i = 0; i < 2; ++i)
#pragma unroll
        for (int j = 0; j < 4; ++j)
            acc[i][j] = (f32x4){0.f, 0.f, 0.f, 0.f};

    for (int k0 = 0; k0 < K; k0 += 32) {
#pragma unroll
        for (int t = 0; t < 4; ++t) {
            const int wr = wave * 64 + t * 16 + sr;
            async16(Wt + (size_t)wr * K + k0 + sc,
                    (void*)(Bs + (wave * 4 + t) * 512 + lane * 8));
        }

        {
            const int kk = k0 + ac;
            const size_t grow = (size_t)(row0 + ar);

            bf16x4 lo = *(const bf16x4*)(Pprev + grow * 256 + colOff + kk);
            bf16x4 hi = *(const bf16x4*)(Pprev + grow * 256 + colOff + kk + 128);
            bf16x4 rv;
            if (RES) rv = *(const bf16x4*)(res + grow * 128 + kk);

            float4 a0 = *(const float4*)&tScA[kk];
            float4 h0 = *(const float4*)&tShA[kk];
            float4 g0 = *(const float4*)&tScG[kk];
            float4 s0 = *(const float4*)&tShG[kk];
            float scA[4] = {a0.x, a0.y, a0.z, a0.w};
            float shA[4] = {h0.x, h0.y, h0.z, h0.w};
            float scG[4] = {g0.x, g0.y, g0.z, g0.w};
            float shG[4] = {s0.x, s0.y, s0.z, s0.w};

            bf16x4 o4;
#pragma unroll
            for (int e = 0; e < 4; ++e) {
                float na = b2f((unsigned short)lo[e]) * scA[e] + shA[e];
                float ng = b2f((unsigned short)hi[e]) * scG[e] + shG[e];
                float v = na * (1.0f / (1.0f + __expf(-ng)));
                if (RES) v = (v + b2f((unsigned short)rv[e])) * SQRT_HALF;
                o4[e] = (short)f2b(v);
            }
            *(bf16x4*)(As + ar * 32 + ac) = o4;
            if (WRITE_H)
                *(bf16x4*)(hOut + grow * 128 + kk) = o4;
        }
        __syncthreads();

        bf16x8 af[2], bfr[4];
#pragma unroll
        for (int i = 0; i < 2; ++i)
            af[i] = *(const bf16x8*)(As + (i * 16 + fm) * 32 + fq);
#pragma unroll
        for (int j = 0; j < 4; ++j)
            bfr[j] = *(const bf16x8*)(Bs + (wave * 64 + j * 16 + fm) * 32 + fq);
#pragma unroll
        for (int i = 0; i < 2; ++i)
#pragma unroll
            for (int j = 0; j < 4; ++j)
                acc[i][j] = __builtin_amdgcn_mfma_f32_16x16x32_bf16(af[i], bfr[j], acc[i][j], 0, 0, 0);
        __syncthreads();
    }

    gemm_epilogue(acc, row0, wave, lane, tid, bcp, redS, redQ, Pout, statsOut);
}

__global__ __launch_bounds__(256) void coef_ent(const unsigned short* __restrict__ Pc,
                                                const float* __restrict__ stats,
                                                const float* __restrict__ gc,
                                                const float* __restrict__ bc,
                                                const unsigned short* __restrict__ cmpl,
                                                float* __restrict__ ent) {
    const int w    = threadIdx.x >> 6;
    const int lane = threadIdx.x & 63;
    const int row  = blockIdx.x * 4 + w;
    const int c    = lane << 2;
    __shared__ float went[4];

    float sS[4] = {0.f, 0.f, 0.f, 0.f}, sQ[4] = {0.f, 0.f, 0.f, 0.f};
#pragma unroll
    for (int cp = 0; cp < NCPY; ++cp) {
        float4 a = *(const float4*)&stats[cp * 512 + c];
        float4 q = *(const float4*)&stats[cp * 512 + 256 + c];
        sS[0] += a.x; sS[1] += a.y; sS[2] += a.z; sS[3] += a.w;
        sQ[0] += q.x; sQ[1] += q.y; sQ[2] += q.z; sQ[3] += q.w;
    }
    float4 gv = *(const float4*)&gc[c];
    float4 bv = *(const float4*)&bc[c];
    const float* gvv = (const float*)&gv; const float* bvv = (const float*)&bv;

    float scl[4], shf[4];
#pragma unroll
    for (int e = 0; e < 4; ++e) {
        float mean = sS[e] * INV_B, var = sQ[e] * INV_B - mean * mean;
        scl[e] = gvv[e] * rsqrtf(var + BN_EPS);
        shf[e] = bvv[e] - mean * scl[e];
    }

    const size_t idx = (size_t)row * 256 + c;
    ushort4 pu = *(const ushort4*)(Pc + idx);
    const unsigned short* puv = (const unsigned short*)&pu;
    ushort4 cu = *(const ushort4*)(cmpl + idx);
    const unsigned short* cuv = (const unsigned short*)&cu;

    float l[4];
#pragma unroll
    for (int e = 0; e < 4; ++e)
        l[e] = (b2f(puv[e]) * scl[e] + shf[e]) * b2f(cuv[e]);

    float mx = waveMaxAll(fmaxf(fmaxf(l[0], l[1]), fmaxf(l[2], l[3])));
    float e0 = __expf(l[0] - mx), e1 = __expf(l[1] - mx),
          e2 = __expf(l[2] - mx), e3 = __expf(l[3] - mx);
    float inv = 1.0f / waveSumAll(e0 + e1 + e2 + e3);

    float m[4] = {e0 * inv, e1 * inv, e2 * inv, e3 * inv};

    float et = -m[0] * __logf(m[0] + SM_EPS) - m[1] * __logf(m[1] + SM_EPS)
             - m[2] * __logf(m[2] + SM_EPS) - m[3] * __logf(m[3] + SM_EPS);
    et = waveSumAll(et);
    if (lane == 0) went[w] = et;
    __syncthreads();
    if (threadIdx.x == 0) {
        float v = went[0] + went[1] + went[2] + went[3];
        atomicAdd(&ent[(blockIdx.x & 255) << 5], v * (INV_B * 0.2f));
    }
}

__global__ __launch_bounds__(64) void write_ent(const float* __restrict__ ent,
                                                float* __restrict__ dst) {
    const int lane = threadIdx.x;
    float v = 0.f;
#pragma unroll
    for (int i = 0; i < 4; ++i) v += ent[(lane + 64 * i) << 5];
    v = waveSumAll(v);
    if (lane == 0) dst[0] = v;
}

// ---------------- host orchestration ----------------
extern "C" void kernel_launch(void* const* d_in, const int* in_sizes, int n_in,
                              void* d_out, int out_size, void* d_ws, size_t ws_size,
                              hipStream_t stream) {
    const float* x     = (const float*)d_in[0];
    const float* enc_g = (const float*)d_in[1];
    const float* enc_b = (const float*)d_in[2];
    const float* W1 = (const float*)d_in[3];
    const float* g1 = (const float*)d_in[4];
    const float* b1 = (const float*)d_in[5];
    const float* W2 = (const float*)d_in[6];
    const float* g2 = (const float*)d_in[7];
    const float* b2 = (const float*)d_in[8];
    const float* W3 = (const float*)d_in[9];
    const float* g3 = (const float*)d_in[10];
    const float* b3 = (const float*)d_in[11];
    const float* W4 = (const float*)d_in[12];
    const float* g4 = (const float*)d_in[13];
    const float* b4 = (const float*)d_in[14];
    const float* Wc = (const float*)d_in[15];
    const float* gc = (const float*)d_in[16];
    const float* bc = (const float*)d_in[17];
    float* out = (float*)d_out;

    const size_t NBF = (size_t)BSZ * FDIM;
    const size_t NBH = (size_t)BSZ * HDIM;

    unsigned short* xb     = (unsigned short*)d_ws;
    unsigned short* masked = xb + NBF;            // fallback ping buffer; mega: bar lives here
    unsigned short* Pb1    = masked + NBF;
    unsigned short* h1     = Pb1 + NBF;
    unsigned short* h2     = h1 + NBH;
    unsigned short* h3     = h2 + NBH;
    unsigned short* cmpl   = h3 + NBH;
    unsigned short* W1t    = cmpl + NBF;
    unsigned short* W2t    = W1t + 65536;
    unsigned short* W3t    = W2t + 32768;
    unsigned short* W4t    = W3t + 163840;
    unsigned short* Wct    = W4t + 163840;
    float* stats = (float*)(Wct + 81920);
    float* ent   = stats + 26 * SLOT;
    unsigned int* bar = (unsigned int*)masked;    // 65 lines x 128B, mega only

    unsigned short* Pb2 = masked;

    // one-time occupancy check (host-side query; capture-safe)
    static int s_ok = -1;
    if (s_ok < 0) {
        int occ = 0, mpc = 0, dev = 0;
        hipGetDevice(&dev);
        hipDeviceProp_t prop;
        if (hipGetDeviceProperties(&prop, dev) == hipSuccess) mpc = prop.multiProcessorCount;
        if (hipOccupancyMaxActiveBlocksPerMultiprocessor(
                &occ, reinterpret_cast<const void*>(mega), 256, 0) != hipSuccess) occ = 0;
        s_ok = (occ >= 4 && occ * mpc >= GRID) ? 1 : 0;
    }

    hipMemsetAsync(stats, 0, (26 * SLOT + 256 * 32) * sizeof(float), stream);

    if (s_ok) {
        hipMemsetAsync(bar, 0, 65 * 32 * sizeof(unsigned int), stream);
        mega<<<GRID, 256, 0, stream>>>(
            x, enc_g, enc_b, g1, b1, g2, b2, g3, b3, g4, b4, gc, bc,
            W1, W2, W3, W4, Wc, W1t, W2t, W3t, W4t, Wct,
            xb, cmpl, stats, ent, bar, out);
        return;
    }

    // -------- fallback: proven multi-kernel pipeline --------
    prep_w<<<dim3(17, 8), 256, 0, stream>>>(W1, W2, W3, W4, Wc, W1t, W2t, W3t, W4t, Wct);
    colstats<<<1024, 256, 0, stream>>>(x, stats);
    norm_x<<<8192, 256, 0, stream>>>(x, stats, enc_g, enc_b, xb, out);

    for (int ni = 0; ni < 5; ++ni) {
        float* s1 = stats + (size_t)(1 + ni * 5 + 0) * SLOT;
        float* s2 = stats + (size_t)(1 + ni * 5 + 1) * SLOT;
        float* s3 = stats + (size_t)(1 + ni * 5 + 2) * SLOT;
        float* s4 = stats + (size_t)(1 + ni * 5 + 3) * SLOT;
        float* s5 = stats + (size_t)(1 + ni * 5 + 4) * SLOT;

        if (ni == 0) {
            gemm_bf16<<<1024, 256, 0, stream>>>(xb, W1t, 256, Pb1, s1);
        } else {
            float* s5p = stats + (size_t)(1 + (ni - 1) * 5 + 4) * SLOT;
            if (ni == 1)
                gemm_mask<0><<<1024, 256, 0, stream>>>(
                    Pb1, s5p, gc, bc, xb, cmpl, ent, W1t, Pb1, s1);
            else
                gemm_mask<1><<<1024, 256, 0, stream>>>(
                    Pb1, s5p, gc + (ni - 1) * 256, bc + (ni - 1) * 256,
                    xb, cmpl, ent, W1t, Pb1, s1);
        }

        gemm_glu<false, true><<<1024, 256, 0, stream>>>(
            Pb1, s1, g1, b1, nullptr, 0, W2t, 128, Pb2, s2, h1);
        gemm_glu<true, true><<<1024, 256, 0, stream>>>(
            Pb2, s2, g2, b2, h1, 0, W3t + (size_t)ni * 32768, 128, Pb1, s3, h2);
        gemm_glu<true, true><<<1024, 256, 0, stream>>>(
            Pb1, s3, g3 + ni * 256, b3 + ni * 256, h2, 0,
            W4t + (size_t)ni * 32768, 128, Pb2, s4, h3);
        gemm_glu<true, false><<<1024, 256, 0, stream>>>(
            Pb2, s4, g4 + ni * 256, b4 + ni * 256, h3 + 64, 64,
            Wct + (size_t)ni * 16384, 64, Pb1, s5, nullptr);
    }

    coef_ent<<<BSZ / 4, 256, 0, stream>>>(
        Pb1, stats + (size_t)(1 + 4 * 5 + 4) * SLOT,
        gc + 4 * 256, bc + 4 * 256, cmpl, ent);

    write_ent<<<1, 64, 0, stream>>>(ent, out + (size_t)BSZ * OUTD);
}